// Round 6
// baseline (6153.616 us; speedup 1.0000x reference)
//
#include <hip/hip_runtime.h>
#include <math.h>

#define H    1024
#define C    151
#define E    200
#define DIN  2048
#define T    32
#define B    128
#define SIXH  (6*H)   // 6144
#define FIVEH (5*H)   // 5120
#define KTOT  DIN     // 2048
#define NEMB  (C+1)   // 152
#define NWG   160     // persistent blocks; 160*32 = 5120 cols
#define COLS  32      // ps columns per WG
#define GUARD (1 << 16)   // spin bailout: bounded wrong-answer beats container-killing hang

typedef _Float16 f16x8 __attribute__((ext_vector_type(8)));
typedef _Float16 f16x4 __attribute__((ext_vector_type(4)));
typedef float    f32x4 __attribute__((ext_vector_type(4)));

#define GLOAD_LDS16(g, l) __builtin_amdgcn_global_load_lds( \
    (const __attribute__((address_space(1))) unsigned int*)(g), \
    (__attribute__((address_space(3))) unsigned int*)(l), 16, 0, 0)

// ---------------- init ----------------
__global__ void init_kernel(float* h, float* c, _Float16* hhi, _Float16* hlo,
                            int* eidx, int* ebuf, int* flags) {
    int i = blockIdx.x * blockDim.x + threadIdx.x;
    if (i < B * H) { h[i] = 0.f; c[i] = 0.f; }
    if (i < 2 * B * H) { hhi[i] = (_Float16)0.f; hlo[i] = (_Float16)0.f; }
    if (i < B) eidx[i] = 0;
    if (i < 2 * B) ebuf[i] = 0;
    if (i < 224 * 16) flags[i] = 0;
}

// ---------------- X [4096][2048] fp32 -> hi/lo fp16 ----------------
__global__ void cvt_x(const float* __restrict__ X, _Float16* __restrict__ hi,
                      _Float16* __restrict__ lo) {
    size_t i = ((size_t)blockIdx.x * 256 + threadIdx.x) * 4;
    float4 v = *(const float4*)(X + i);
    f16x4 h, l;
    h.x = (_Float16)v.x; l.x = (_Float16)(v.x - (float)h.x);
    h.y = (_Float16)v.y; l.y = (_Float16)(v.y - (float)h.y);
    h.z = (_Float16)v.z; l.z = (_Float16)(v.z - (float)h.z);
    h.w = (_Float16)v.w; l.w = (_Float16)(v.w - (float)h.w);
    *(f16x4*)(hi + i) = h;
    *(f16x4*)(lo + i) = l;
}

// ---------------- W [KR][NC] fp32 -> out [NC][KR] hi/lo fp16 (transposed) ----------------
template<int KR, int NC>
__global__ void cvt_wT(const float* __restrict__ W, _Float16* __restrict__ hi,
                       _Float16* __restrict__ lo) {
    __shared__ float tile[32][33];
    int n0 = blockIdx.x * 32, k0 = blockIdx.y * 32;
    int tx = threadIdx.x & 31, ty = threadIdx.x >> 5;
    #pragma unroll
    for (int i = 0; i < 4; ++i) {
        int k = ty + i * 8;
        tile[k][tx] = W[(size_t)(k0 + k) * NC + n0 + tx];
    }
    __syncthreads();
    #pragma unroll
    for (int i = 0; i < 4; ++i) {
        int n = ty + i * 8;
        float v = tile[tx][n];
        _Float16 h = (_Float16)v;
        size_t o = (size_t)(n0 + n) * KR + k0 + tx;
        hi[o] = h;
        lo[o] = (_Float16)(v - (float)h);
    }
}

// ---------------- Etab[k][n] = sum_e embed[k][e] * Wi[DIN+e][n]  (fp32) ----------------
__global__ void etab_kernel(const float* __restrict__ embed,
                            const float* __restrict__ Wi,
                            float* __restrict__ Etab) {
    int n = blockIdx.x * 256 + threadIdx.x;
    int k = blockIdx.y;
    const float* wp = Wi + (size_t)DIN * SIXH + n;
    const float* ep = embed + k * E;
    float acc = 0.f;
    #pragma unroll 8
    for (int e = 0; e < E; ++e)
        acc = fmaf(ep[e], wp[(size_t)e * SIXH], acc);
    Etab[(size_t)k * SIXH + n] = acc;
}

// ---------------- P = X @ Wi_x + bi, fp16x3 MFMA. tile 128x128 ----------
__global__ __launch_bounds__(256) void big_gemm_mfma(
    const _Float16* __restrict__ Ahi, const _Float16* __restrict__ Alo,
    const _Float16* __restrict__ Bhi, const _Float16* __restrict__ Blo,
    const float* __restrict__ bi, float* __restrict__ P)
{
    __shared__ __align__(16) _Float16 sAh[128 * 32];
    __shared__ __align__(16) _Float16 sAl[128 * 32];
    __shared__ __align__(16) _Float16 sBh[128 * 32];
    __shared__ __align__(16) _Float16 sBl[128 * 32];
    const int tid = threadIdx.x;
    const int n0 = blockIdx.x * 128;
    const int m0 = blockIdx.y * 128;
    const int lane = tid & 63, w = tid >> 6;
    const int wm = (w >> 1) * 64, wn = (w & 1) * 64;
    const int lr = lane & 15, lq = lane >> 4;

    f32x4 acc[4][4];
    #pragma unroll
    for (int i = 0; i < 4; ++i)
        #pragma unroll
        for (int j = 0; j < 4; ++j)
            acc[i][j] = (f32x4){0.f, 0.f, 0.f, 0.f};

    const int row0 = tid >> 2;
    const int kc = tid & 3;
    const int kcs = kc ^ ((row0 >> 1) & 3);
    const int sw = (lq ^ ((lr >> 1) & 3)) * 8;

    for (int k0 = 0; k0 < KTOT; k0 += 32) {
        #pragma unroll
        for (int i = 0; i < 2; ++i) {
            int row = row0 + i * 64;
            size_t ga = (size_t)(m0 + row) * KTOT + k0 + kcs * 8;
            size_t gb = (size_t)(n0 + row) * KTOT + k0 + kcs * 8;
            int loff = (i * 256 + tid) * 8;
            GLOAD_LDS16(Ahi + ga, sAh + loff);
            GLOAD_LDS16(Alo + ga, sAl + loff);
            GLOAD_LDS16(Bhi + gb, sBh + loff);
            GLOAD_LDS16(Blo + gb, sBl + loff);
        }
        __syncthreads();
        f16x8 ah[4], al[4], bh[4], bl[4];
        #pragma unroll
        for (int i = 0; i < 4; ++i) {
            ah[i] = *(const f16x8*)&sAh[(wm + i * 16 + lr) * 32 + sw];
            al[i] = *(const f16x8*)&sAl[(wm + i * 16 + lr) * 32 + sw];
            bh[i] = *(const f16x8*)&sBh[(wn + i * 16 + lr) * 32 + sw];
            bl[i] = *(const f16x8*)&sBl[(wn + i * 16 + lr) * 32 + sw];
        }
        #pragma unroll
        for (int i = 0; i < 4; ++i)
            #pragma unroll
            for (int j = 0; j < 4; ++j) {
                acc[i][j] = __builtin_amdgcn_mfma_f32_16x16x32_f16(ah[i], bh[j], acc[i][j], 0, 0, 0);
                acc[i][j] = __builtin_amdgcn_mfma_f32_16x16x32_f16(ah[i], bl[j], acc[i][j], 0, 0, 0);
                acc[i][j] = __builtin_amdgcn_mfma_f32_16x16x32_f16(al[i], bh[j], acc[i][j], 0, 0, 0);
            }
        __syncthreads();
    }
    #pragma unroll
    for (int i = 0; i < 4; ++i)
        #pragma unroll
        for (int j = 0; j < 4; ++j) {
            int gcol = n0 + wn + j * 16 + lr;
            float bv = bi[gcol];
            #pragma unroll
            for (int r = 0; r < 4; ++r) {
                int grow = m0 + wm + i * 16 + lq * 4 + r;
                P[(size_t)grow * SIXH + gcol] = acc[i][j][r] + bv;
            }
        }
}

// ================= persistent dataflow loop (cooperative launch) =================
// Point-to-point flags (no global barriers):
//   gemm_f[160]: WG's ps-slice for step t ready (flag value t+1)
//   gate_f[32] : gate-WG jg's h j-slice for step t ready (t+1)
//   pred_f[32] : pred-WG's eidx rows for step t ready (t+1)
// Dependence closure (R5 WAR fix): gates wait ALL 160 gemm_f >= t+1 —
// covers ps RAW (5 producers) AND h WAR (all 160 WGs read h in GEMM(t-1);
// gemm_f>=t+1 => GEMM(t) done => GEMM(t-1) done by program order).
// GEMM(t) loop-top waits gate_f >= t (h RAW + ps WAR via gates(t-1) done).
// Gates also wait pred_f >= t (ebuf RAW from pred(t-1), hfp WAR vs pred(t-2)).
// Preds wait gate_f >= t+1 (hfp RAW; ebuf WAR vs gates(t-1) subsumed).
// Chain is well-founded: GEMM(t)<-gates(t-1); gates(t)<-{GEMM(t),preds(t-1)};
// preds(t)<-gates(t). No cycle. All spins carry GUARD bailout.
__global__ __launch_bounds__(256, 1) void fused_loop(
    const float* __restrict__ P,
    const float* __restrict__ Etab,
    const float* __restrict__ bs,
    const _Float16* __restrict__ WsThi,
    const _Float16* __restrict__ WsTlo,
    _Float16* __restrict__ hhi,      // [2][B*H]
    _Float16* __restrict__ hlo,      // [2][B*H]
    float* __restrict__ hfp,         // [2][B*H] exact fp32 h for pred
    float* __restrict__ psb,         // [2][B*FIVEH]
    const float* __restrict__ Wo,
    const float* __restrict__ bo,
    const int* __restrict__ labels,
    float* __restrict__ dists,
    float* __restrict__ comms,
    int* __restrict__ ebuf,          // [2][B]
    int* flags)
{
    __shared__ __align__(16) _Float16 sBh[COLS * H];   // 64 KB, XOR-swizzled
    __shared__ __align__(16) _Float16 sBl[COLS * H];   // 64 KB

    const int wg  = blockIdx.x;
    const int tid = threadIdx.x;
    const int n0  = wg * COLS;
    const int lane = tid & 63, w = tid >> 6;
    const int lr = lane & 15, lq = lane >> 4;
    int* gemm_f = flags;              // stride-16 ints (64B padded lines)
    int* gate_f = flags + 160 * 16;
    int* pred_f = flags + 192 * 16;

    // ---- stage Ws slice into LDS, swizzled: granule byte ^= (col&7)<<4 ----
    for (int gi = tid; gi < COLS * (H / 8); gi += 256) {
        int col = gi >> 7;
        int kg  = gi & 127;
        int dst = (col * (H * 2) + kg * 16) ^ ((col & 7) << 4);
        *(f16x8*)((char*)sBh + dst) = *(const f16x8*)&WsThi[(size_t)(n0 + col) * H + kg * 8];
        *(f16x8*)((char*)sBl + dst) = *(const f16x8*)&WsTlo[(size_t)(n0 + col) * H + kg * 8];
    }

    // gate role state (wg<32): jc = tid&31, bg = tid>>5; handles b = bg*16+i
    const int jg = wg;
    const int jc = tid & 31, bg = tid >> 5;
    float creg[16];
    float bsv[5];
    if (wg < 32) {
        #pragma unroll
        for (int i = 0; i < 16; ++i) creg[i] = 0.f;
        #pragma unroll
        for (int k = 0; k < 5; ++k) bsv[k] = bs[k * H + jg * 32 + jc];
    }
    __syncthreads();

    const int mrow0 = w * 32;

    for (int t = 0; t < T; ++t) {
        const int par = t & 1;

        // ---- wait: h(t-1) ready = all 32 gate flags >= t (t=0 trivial) ----
        {
            int ok, guard = 0;
            do {
                int v = t;
                if (tid < 32)
                    v = __hip_atomic_load(&gate_f[tid * 16], __ATOMIC_RELAXED, __HIP_MEMORY_SCOPE_AGENT);
                ok = __syncthreads_and(v >= t);
                if (!ok) __builtin_amdgcn_s_sleep(1);
            } while (!ok && ++guard < GUARD);
            __builtin_amdgcn_fence(__ATOMIC_ACQUIRE, "agent");
        }

        // ---- GEMM: ps[par][:, n0..n0+32) = h(t-1) @ Ws-slice, fp16x3 ----
        {
            const _Float16* hA = hhi + (size_t)(par ^ 1) * (B * H);
            const _Float16* lA = hlo + (size_t)(par ^ 1) * (B * H);
            float* psw = psb + (size_t)par * (B * FIVEH);
            f32x4 acc[2][2];
            #pragma unroll
            for (int i = 0; i < 2; ++i)
                #pragma unroll
                for (int j = 0; j < 2; ++j)
                    acc[i][j] = (f32x4){0.f, 0.f, 0.f, 0.f};

            #pragma unroll 8
            for (int k0 = 0; k0 < H; k0 += 32) {
                f16x8 ah[2], al[2], bh[2], bl[2];
                #pragma unroll
                for (int i = 0; i < 2; ++i) {
                    size_t ho = (size_t)(mrow0 + i * 16 + lr) * H + k0 + lq * 8;
                    ah[i] = *(const f16x8*)&hA[ho];
                    al[i] = *(const f16x8*)&lA[ho];
                }
                #pragma unroll
                for (int j = 0; j < 2; ++j) {
                    int col = j * 16 + lr;
                    int off = (col * (H * 2) + (k0 + lq * 8) * 2) ^ ((col & 7) << 4);
                    bh[j] = *(const f16x8*)((const char*)sBh + off);
                    bl[j] = *(const f16x8*)((const char*)sBl + off);
                }
                #pragma unroll
                for (int i = 0; i < 2; ++i)
                    #pragma unroll
                    for (int j = 0; j < 2; ++j) {
                        acc[i][j] = __builtin_amdgcn_mfma_f32_16x16x32_f16(ah[i], bh[j], acc[i][j], 0, 0, 0);
                        acc[i][j] = __builtin_amdgcn_mfma_f32_16x16x32_f16(ah[i], bl[j], acc[i][j], 0, 0, 0);
                        acc[i][j] = __builtin_amdgcn_mfma_f32_16x16x32_f16(al[i], bh[j], acc[i][j], 0, 0, 0);
                    }
            }
            #pragma unroll
            for (int i = 0; i < 2; ++i)
                #pragma unroll
                for (int j = 0; j < 2; ++j)
                    #pragma unroll
                    for (int r = 0; r < 4; ++r)
                        psw[(size_t)(mrow0 + i * 16 + lq * 4 + r) * FIVEH + n0 + j * 16 + lr] = acc[i][j][r];
        }
        __syncthreads();
        if (tid == 0)
            __hip_atomic_fetch_add(&gemm_f[wg * 16], 1, __ATOMIC_RELEASE, __HIP_MEMORY_SCOPE_AGENT);

        // ---- gate role: j-slice jg, all b ----
        if (wg < 32) {
            // wait ALL 160 gemm flags >= t+1 (ps RAW + h WAR closure)
            {
                int ok, guard = 0;
                do {
                    int v = t + 1;
                    if (tid < NWG)
                        v = __hip_atomic_load(&gemm_f[tid * 16], __ATOMIC_RELAXED, __HIP_MEMORY_SCOPE_AGENT);
                    ok = __syncthreads_and(v >= t + 1);
                    if (!ok) __builtin_amdgcn_s_sleep(1);
                } while (!ok && ++guard < GUARD);
            }
            // wait eidx(t-1): all 32 pred flags >= t (t=0 trivial)
            {
                int ok, guard = 0;
                do {
                    int v = t;
                    if (tid < 32)
                        v = __hip_atomic_load(&pred_f[tid * 16], __ATOMIC_RELAXED, __HIP_MEMORY_SCOPE_AGENT);
                    ok = __syncthreads_and(v >= t);
                    if (!ok) __builtin_amdgcn_s_sleep(1);
                } while (!ok && ++guard < GUARD);
            }
            __builtin_amdgcn_fence(__ATOMIC_ACQUIRE, "agent");

            const float* psr = psb + (size_t)par * (B * FIVEH);
            const int*   er  = ebuf + (par ^ 1) * B;
            _Float16* hhw = hhi + (size_t)par * (B * H);
            _Float16* hlw = hlo + (size_t)par * (B * H);
            float*    hfw = hfp + (size_t)par * (B * H);
            const int j = jg * 32 + jc;
            #pragma unroll
            for (int i = 0; i < 16; ++i) {
                const int b = bg * 16 + i;
                const float* prow = P + (size_t)(t * B + b) * SIXH + j;
                const float* erow = Etab + (size_t)er[b] * SIXH + j;
                const float* pvp  = psr + (size_t)b * FIVEH + j;
                float gv[5];
                #pragma unroll
                for (int k = 0; k < 5; ++k)
                    gv[k] = prow[k * H] + erow[k * H] + pvp[k * H] + bsv[k];
                float pi5 = prow[5 * H] + erow[5 * H];
                float ig = 1.f / (1.f + expf(-gv[0]));
                float fg = 1.f / (1.f + expf(-gv[1]));
                float mi = tanhf(gv[2]);
                float og = 1.f / (1.f + expf(-gv[3]));
                float hw2 = 1.f / (1.f + expf(-gv[4]));
                float cn = ig * mi + fg * creg[i];
                float out = og * tanhf(cn);
                float hn = hw2 * out + (1.f - hw2) * pi5;
                creg[i] = cn;
                hfw[(size_t)b * H + j] = hn;
                _Float16 hh = (_Float16)hn;
                hhw[(size_t)b * H + j] = hh;
                hlw[(size_t)b * H + j] = (_Float16)(hn - (float)hh);
            }
            __syncthreads();
            if (tid == 0)
                __hip_atomic_fetch_add(&gate_f[jg * 16], 1, __ATOMIC_RELEASE, __HIP_MEMORY_SCOPE_AGENT);
        }

        // ---- pred role: 4 batch rows, one per wave; overlaps next GEMM on other WGs ----
        if (wg >= 128) {
            const int pi = wg - 128;
            {
                int ok, guard = 0;
                do {
                    int v = t + 1;
                    if (tid < 32)
                        v = __hip_atomic_load(&gate_f[tid * 16], __ATOMIC_RELAXED, __HIP_MEMORY_SCOPE_AGENT);
                    ok = __syncthreads_and(v >= t + 1);
                    if (!ok) __builtin_amdgcn_s_sleep(1);
                } while (!ok && ++guard < GUARD);
            }
            __builtin_amdgcn_fence(__ATOMIC_ACQUIRE, "agent");

            const int b = pi * 4 + w;
            const float* hrow = hfp + (size_t)par * (B * H) + (size_t)b * H;
            const int c0 = lane, c1 = lane + 64, c2 = lane + 128;
            float a0 = bo[c0];                       // c0 < 64 < C always
            float a1 = (c1 < C) ? bo[c1] : 0.f;
            float a2 = (c2 < C) ? bo[c2] : 0.f;
            #pragma unroll 8
            for (int k = 0; k < H; ++k) {
                float hk = hrow[k];
                const float* wr = Wo + (size_t)k * C;
                a0 = fmaf(hk, wr[c0], a0);
                if (c1 < C) a1 = fmaf(hk, wr[c1], a1);
                if (c2 < C) a2 = fmaf(hk, wr[c2], a2);
            }
            float* drow = dists + (size_t)(t * B + b) * C;
            drow[c0] = a0;
            if (c1 < C) drow[c1] = a1;
            if (c2 < C) drow[c2] = a2;
            // argmax over classes >=1, lowest index wins ties
            float bv2 = -1e30f; int bi2 = 0x7fffffff;
            if (c0 >= 1) { bv2 = a0; bi2 = c0; }
            if (c1 < C && (a1 > bv2 || (a1 == bv2 && c1 < bi2))) { bv2 = a1; bi2 = c1; }
            if (c2 < C && (a2 > bv2 || (a2 == bv2 && c2 < bi2))) { bv2 = a2; bi2 = c2; }
            #pragma unroll
            for (int s = 32; s > 0; s >>= 1) {
                float v2 = __shfl_down(bv2, s, 64);
                int   i2 = __shfl_down(bi2, s, 64);
                if (v2 > bv2 || (v2 == bv2 && i2 < bi2)) { bv2 = v2; bi2 = i2; }
            }
            if (lane == 0) {
                int lt = labels[t * B + b];
                int comm = (lt == 0) ? bi2 : lt;
                comms[t * B + b] = (float)comm;
                ebuf[par * B + b] = comm + 1;
            }
            __syncthreads();
            if (tid == 0)
                __hip_atomic_fetch_add(&pred_f[pi * 16], 1, __ATOMIC_RELEASE, __HIP_MEMORY_SCOPE_AGENT);
        }
    }
}

// ================= fallback per-timestep kernels (used only if coop launch fails) =====
__global__ __launch_bounds__(256) void ps_mfma(
    const _Float16* __restrict__ Ahi, const _Float16* __restrict__ Alo,
    const _Float16* __restrict__ Bhi, const _Float16* __restrict__ Blo,
    float* __restrict__ ps)
{
    __shared__ __align__(16) _Float16 sAh[64 * 32];
    __shared__ __align__(16) _Float16 sAl[64 * 32];
    __shared__ __align__(16) _Float16 sBh[64 * 32];
    __shared__ __align__(16) _Float16 sBl[64 * 32];
    const int tid = threadIdx.x;
    const int n0 = blockIdx.x * 64;
    const int m0 = blockIdx.y * 64;
    const int lane = tid & 63, w = tid >> 6;
    const int wm = (w >> 1) * 32, wn = (w & 1) * 32;
    const int lr = lane & 15, lq = lane >> 4;

    f32x4 acc[2][2];
    #pragma unroll
    for (int i = 0; i < 2; ++i)
        #pragma unroll
        for (int j = 0; j < 2; ++j)
            acc[i][j] = (f32x4){0.f, 0.f, 0.f, 0.f};

    const int row = tid >> 2;
    const int kc = tid & 3;

    for (int k0 = 0; k0 < H; k0 += 32) {
        size_t ga = (size_t)(m0 + row) * H + k0 + kc * 8;
        size_t gb = (size_t)(n0 + row) * H + k0 + kc * 8;
        int loff = tid * 8;
        GLOAD_LDS16(Ahi + ga, sAh + loff);
        GLOAD_LDS16(Alo + ga, sAl + loff);
        GLOAD_LDS16(Bhi + gb, sBh + loff);
        GLOAD_LDS16(Blo + gb, sBl + loff);
        __syncthreads();
        f16x8 ah[2], al[2], bh[2], bl[2];
        #pragma unroll
        for (int i = 0; i < 2; ++i) {
            ah[i] = *(const f16x8*)&sAh[(wm + i * 16 + lr) * 32 + lq * 8];
            al[i] = *(const f16x8*)&sAl[(wm + i * 16 + lr) * 32 + lq * 8];
            bh[i] = *(const f16x8*)&sBh[(wn + i * 16 + lr) * 32 + lq * 8];
            bl[i] = *(const f16x8*)&sBl[(wn + i * 16 + lr) * 32 + lq * 8];
        }
        #pragma unroll
        for (int i = 0; i < 2; ++i)
            #pragma unroll
            for (int j = 0; j < 2; ++j) {
                acc[i][j] = __builtin_amdgcn_mfma_f32_16x16x32_f16(ah[i], bh[j], acc[i][j], 0, 0, 0);
                acc[i][j] = __builtin_amdgcn_mfma_f32_16x16x32_f16(ah[i], bl[j], acc[i][j], 0, 0, 0);
                acc[i][j] = __builtin_amdgcn_mfma_f32_16x16x32_f16(al[i], bh[j], acc[i][j], 0, 0, 0);
            }
        __syncthreads();
    }
    #pragma unroll
    for (int i = 0; i < 2; ++i)
        #pragma unroll
        for (int j = 0; j < 2; ++j) {
            int gcol = n0 + wn + j * 16 + lr;
            #pragma unroll
            for (int r = 0; r < 4; ++r) {
                int grow = m0 + wm + i * 16 + lq * 4 + r;
                ps[(size_t)grow * FIVEH + gcol] = acc[i][j][r];
            }
        }
}

__global__ void gate_kernel(const float* __restrict__ P,
                            const float* __restrict__ Etab,
                            const float* __restrict__ ps,
                            const float* __restrict__ bs,
                            const int* __restrict__ eidx,
                            float* __restrict__ h,
                            float* __restrict__ c,
                            _Float16* __restrict__ hhi,
                            _Float16* __restrict__ hlo,
                            int t) {
    int j = blockIdx.x * 256 + threadIdx.x;
    int b = blockIdx.y;
    const float* prow = P + (size_t)(t * B + b) * SIXH;
    const float* erow = Etab + (size_t)eidx[b] * SIXH;
    const float* psr  = ps + (size_t)b * FIVEH;
    float g[5];
    #pragma unroll
    for (int k = 0; k < 5; ++k) {
        int col = k * H + j;
        g[k] = prow[col] + erow[col] + psr[col] + bs[col];
    }
    float pi5 = prow[5 * H + j] + erow[5 * H + j];
    float ig = 1.f / (1.f + expf(-g[0]));
    float fg = 1.f / (1.f + expf(-g[1]));
    float mi = tanhf(g[2]);
    float og = 1.f / (1.f + expf(-g[3]));
    float hw = 1.f / (1.f + expf(-g[4]));
    float cv = c[b * H + j];
    float cn = ig * mi + fg * cv;
    float out = og * tanhf(cn);
    float hn = hw * out + (1.f - hw) * pi5;
    c[b * H + j] = cn;
    h[b * H + j] = hn;
    _Float16 hh = (_Float16)hn;
    hhi[b * H + j] = hh;
    hlo[b * H + j] = (_Float16)(hn - (float)hh);
}

__global__ void pred_kernel(const float* __restrict__ h,
                            const float* __restrict__ Wo,
                            const float* __restrict__ bo,
                            const int* __restrict__ labels,
                            float* __restrict__ dists,
                            float* __restrict__ comms,
                            int* __restrict__ eidx,
                            int t) {
    __shared__ float hsb[H];
    __shared__ float vals[256];
    __shared__ int   idxs[256];
    int tid = threadIdx.x;
    int b = blockIdx.x;
    for (int i = tid; i < H / 4; i += 256)
        *(float4*)&hsb[i * 4] = *(const float4*)&h[b * H + i * 4];
    __syncthreads();
    float pred = 0.f;
    if (tid < C) {
        pred = bo[tid];
        #pragma unroll 8
        for (int k = 0; k < H; ++k)
            pred = fmaf(hsb[k], Wo[k * C + tid], pred);
        dists[(size_t)(t * B + b) * C + tid] = pred;
    }
    vals[tid] = (tid >= 1 && tid < C) ? pred : -1e30f;
    idxs[tid] = tid;
    __syncthreads();
    for (int s = 128; s > 0; s >>= 1) {
        if (tid < s) {
            float v2 = vals[tid + s];
            int   i2 = idxs[tid + s];
            if (v2 > vals[tid] || (v2 == vals[tid] && i2 < idxs[tid])) {
                vals[tid] = v2;
                idxs[tid] = i2;
            }
        }
        __syncthreads();
    }
    if (tid == 0) {
        int nzp = idxs[0];
        int lt = labels[t * B + b];
        int comm = (lt == 0) ? nzp : lt;
        comms[t * B + b] = (float)comm;
        eidx[b] = comm + 1;
    }
}

extern "C" void kernel_launch(void* const* d_in, const int* in_sizes, int n_in,
                              void* d_out, int out_size, void* d_ws, size_t ws_size,
                              hipStream_t stream) {
    const float* X      = (const float*)d_in[0];
    const int*   labels = (const int*)  d_in[1];
    const float* embed  = (const float*)d_in[2];
    const float* Wi     = (const float*)d_in[3];
    const float* bi     = (const float*)d_in[4];
    const float* Ws     = (const float*)d_in[5];
    const float* bs     = (const float*)d_in[6];
    const float* Wo     = (const float*)d_in[7];
    const float* bo     = (const float*)d_in[8];

    // Workspace layout — total 211.4 MB, strictly under the 213.5 MB footprint
    // every passing round used (R5's 218.6 MB may have overflowed d_ws).
    char* w = (char*)d_ws;
    float* P      = (float*)w;              w += (size_t)T * B * SIXH * 4;      // 100.7 MB
    float* Etab   = (float*)w;              w += (size_t)NEMB * SIXH * 4;       //   3.7 MB
    float* h      = (float*)w;              w += (size_t)B * H * 4;             // fallback
    float* c      = (float*)w;              w += (size_t)B * H * 4;             // fallback
    _Float16* hhi = (_Float16*)w;           w += (size_t)2 * B * H * 2;         // [2] buffers
    _Float16* hlo = (_Float16*)w;           w += (size_t)2 * B * H * 2;
    int* eidx     = (int*)w;                w += 512;                            // fallback
    int* ebuf     = (int*)w;                w += 1024;                           // [2][B]
    int* flags    = (int*)w;                w += 224 * 16 * 4;
    _Float16* Xhi = (_Float16*)w;           w += (size_t)T * B * KTOT * 2;      //  16.8 MB
    _Float16* Xlo = (_Float16*)w;           w += (size_t)T * B * KTOT * 2;      //  16.8 MB
    _Float16* WiThi = (_Float16*)w;         w += (size_t)SIXH * KTOT * 2;       //  25.2 MB
    _Float16* WiTlo = (_Float16*)w;         w += (size_t)SIXH * KTOT * 2;
    _Float16* WsThi = (_Float16*)w;         w += (size_t)FIVEH * H * 2;         //  10.5 MB
    _Float16* WsTlo = (_Float16*)w;         w += (size_t)FIVEH * H * 2;
    // psb/hfp overlay the dead Xlo region (Xlo only read by big_gemm, which
    // completes before fused_loop; write-before-read inside fused_loop).
    float* psb    = (float*)Xlo;                               // 5.24 MB
    float* hfp    = (float*)((char*)Xlo + (size_t)2 * B * FIVEH * 4);  // 1.05 MB

    float* dists = (float*)d_out;
    float* comms = dists + (size_t)T * B * C;

    init_kernel<<<1024, 256, 0, stream>>>(h, c, hhi, hlo, eidx, ebuf, flags);
    cvt_x<<<(T * B * KTOT) / (256 * 4), 256, 0, stream>>>(X, Xhi, Xlo);
    cvt_wT<KTOT, SIXH><<<dim3(SIXH / 32, KTOT / 32), 256, 0, stream>>>(Wi, WiThi, WiTlo);
    cvt_wT<H, FIVEH><<<dim3(FIVEH / 32, H / 32), 256, 0, stream>>>(Ws, WsThi, WsTlo);
    etab_kernel<<<dim3(SIXH / 256, NEMB), 256, 0, stream>>>(embed, Wi, Etab);
    big_gemm_mfma<<<dim3(SIXH / 128, (T * B) / 128), 256, 0, stream>>>(Xhi, Xlo, WiThi, WiTlo, bi, P);

    void* args[] = {(void*)&P, (void*)&Etab, (void*)&bs, (void*)&WsThi, (void*)&WsTlo,
                    (void*)&hhi, (void*)&hlo, (void*)&hfp, (void*)&psb, (void*)&Wo,
                    (void*)&bo, (void*)&labels, (void*)&dists, (void*)&comms,
                    (void*)&ebuf, (void*)&flags};
    hipError_t err = hipLaunchCooperativeKernel((void*)fused_loop, dim3(NWG), dim3(256),
                                                args, 0, stream);
    if (err != hipSuccess) {
        // fallback: per-timestep loop (psb overlay is safe: Xlo dead after big_gemm)
        for (int t = 0; t < T; ++t) {
            ps_mfma<<<dim3(FIVEH / 64, B / 64), 256, 0, stream>>>(hhi, hlo, WsThi, WsTlo, psb);
            gate_kernel<<<dim3(H / 256, B), 256, 0, stream>>>(P, Etab, psb, bs, eidx, h, c, hhi, hlo, t);
            pred_kernel<<<B, 256, 0, stream>>>(h, Wo, bo, labels, dists, comms, eidx, t);
        }
    }
}

// Round 7
// 2529.692 us; speedup vs baseline: 2.4326x; 2.4326x over previous
//
#include <hip/hip_runtime.h>
#include <math.h>

#define H    1024
#define C    151
#define E    200
#define DIN  2048
#define T    32
#define B    128
#define SIXH  (6*H)   // 6144
#define FIVEH (5*H)   // 5120
#define KTOT  DIN     // 2048
#define NEMB  (C+1)   // 152
#define NWG   160     // persistent blocks; 160*32 = 5120 cols
#define COLS  32      // ps columns per WG
#define GUARD (1 << 20)

typedef _Float16 f16x8 __attribute__((ext_vector_type(8)));
typedef _Float16 f16x4 __attribute__((ext_vector_type(4)));
typedef float    f32x4 __attribute__((ext_vector_type(4)));

#define GLOAD_LDS16(g, l) __builtin_amdgcn_global_load_lds( \
    (const __attribute__((address_space(1))) unsigned int*)(g), \
    (__attribute__((address_space(3))) unsigned int*)(l), 16, 0, 0)

// ---- flag-array grid barrier (R3, verified): per-WG padded slot, monotonic val ----
// Arrival: uncontended release fetch_add on own 64B slot. Wait: tid<NWG poll one
// slot each + __syncthreads_and. Acquire fence at exit. The RELEASE is where
// CDNA flushes dirty L2 (wbl2); this round minimizes dirty volume via
// non-temporal stores for all cross-WG data so the flush is near-empty.
__device__ __forceinline__ void gbar(int* slots, int tid, int val) {
    __syncthreads();
    if (tid == 0)
        __hip_atomic_fetch_add(&slots[blockIdx.x * 16], 1,
                               __ATOMIC_ACQ_REL, __HIP_MEMORY_SCOPE_AGENT);
    int ok, guard = 0;
    do {
        int v = val;
        if (tid < NWG)
            v = __hip_atomic_load(&slots[tid * 16],
                                  __ATOMIC_RELAXED, __HIP_MEMORY_SCOPE_AGENT);
        ok = __syncthreads_and(v >= val);
        if (!ok) __builtin_amdgcn_s_sleep(1);
    } while (!ok && ++guard < GUARD);
    __builtin_amdgcn_fence(__ATOMIC_ACQUIRE, "agent");
}

// ---------------- init: zero h, c, hhi, hlo, eidx, barrier slots ----------------
__global__ void init_kernel(float* h, float* c, _Float16* hhi, _Float16* hlo,
                            int* eidx, int* bar) {
    int i = blockIdx.x * blockDim.x + threadIdx.x;
    if (i < B * H) {
        h[i] = 0.f; c[i] = 0.f;
        hhi[i] = (_Float16)0.f; hlo[i] = (_Float16)0.f;
    }
    if (i < B) eidx[i] = 0;
    if (i < NWG * 16) bar[i] = 0;
}

// ---------------- X [4096][2048] fp32 -> hi/lo fp16 (same layout) ----------------
__global__ void cvt_x(const float* __restrict__ X, _Float16* __restrict__ hi,
                      _Float16* __restrict__ lo) {
    size_t i = ((size_t)blockIdx.x * 256 + threadIdx.x) * 4;
    float4 v = *(const float4*)(X + i);
    f16x4 h, l;
    h.x = (_Float16)v.x; l.x = (_Float16)(v.x - (float)h.x);
    h.y = (_Float16)v.y; l.y = (_Float16)(v.y - (float)h.y);
    h.z = (_Float16)v.z; l.z = (_Float16)(v.z - (float)h.z);
    h.w = (_Float16)v.w; l.w = (_Float16)(v.w - (float)h.w);
    *(f16x4*)(hi + i) = h;
    *(f16x4*)(lo + i) = l;
}

// ---------------- W [KR][NC] fp32 -> out [NC][KR] hi/lo fp16 (transposed) ----------------
template<int KR, int NC>
__global__ void cvt_wT(const float* __restrict__ W, _Float16* __restrict__ hi,
                       _Float16* __restrict__ lo) {
    __shared__ float tile[32][33];
    int n0 = blockIdx.x * 32, k0 = blockIdx.y * 32;
    int tx = threadIdx.x & 31, ty = threadIdx.x >> 5;   // ty 0..7
    #pragma unroll
    for (int i = 0; i < 4; ++i) {
        int k = ty + i * 8;
        tile[k][tx] = W[(size_t)(k0 + k) * NC + n0 + tx];
    }
    __syncthreads();
    #pragma unroll
    for (int i = 0; i < 4; ++i) {
        int n = ty + i * 8;
        float v = tile[tx][n];              // = W[k0+tx][n0+n]
        _Float16 h = (_Float16)v;
        size_t o = (size_t)(n0 + n) * KR + k0 + tx;
        hi[o] = h;
        lo[o] = (_Float16)(v - (float)h);
    }
}

// ---------------- Etab[k][n] = sum_e embed[k][e] * Wi[DIN+e][n]  (fp32) ----------------
__global__ void etab_kernel(const float* __restrict__ embed,
                            const float* __restrict__ Wi,
                            float* __restrict__ Etab) {
    int n = blockIdx.x * 256 + threadIdx.x;
    int k = blockIdx.y;
    const float* wp = Wi + (size_t)DIN * SIXH + n;
    const float* ep = embed + k * E;
    float acc = 0.f;
    #pragma unroll 8
    for (int e = 0; e < E; ++e)
        acc = fmaf(ep[e], wp[(size_t)e * SIXH], acc);
    Etab[(size_t)k * SIXH + n] = acc;
}

// ---------------- P = X @ Wi_x + bi, fp16x3 MFMA. tile 128x128 ----------
__global__ __launch_bounds__(256) void big_gemm_mfma(
    const _Float16* __restrict__ Ahi, const _Float16* __restrict__ Alo,
    const _Float16* __restrict__ Bhi, const _Float16* __restrict__ Blo,
    const float* __restrict__ bi, float* __restrict__ P)
{
    __shared__ __align__(16) _Float16 sAh[128 * 32];
    __shared__ __align__(16) _Float16 sAl[128 * 32];
    __shared__ __align__(16) _Float16 sBh[128 * 32];
    __shared__ __align__(16) _Float16 sBl[128 * 32];
    const int tid = threadIdx.x;
    const int n0 = blockIdx.x * 128;
    const int m0 = blockIdx.y * 128;
    const int lane = tid & 63, w = tid >> 6;
    const int wm = (w >> 1) * 64, wn = (w & 1) * 64;
    const int lr = lane & 15, lq = lane >> 4;

    f32x4 acc[4][4];
    #pragma unroll
    for (int i = 0; i < 4; ++i)
        #pragma unroll
        for (int j = 0; j < 4; ++j)
            acc[i][j] = (f32x4){0.f, 0.f, 0.f, 0.f};

    const int row0 = tid >> 2;        // 0..63
    const int kc = tid & 3;
    const int kcs = kc ^ ((row0 >> 1) & 3);   // swizzled source chunk
    const int sw = (lq ^ ((lr >> 1) & 3)) * 8; // swizzled read slot (halves)

    for (int k0 = 0; k0 < KTOT; k0 += 32) {
        #pragma unroll
        for (int i = 0; i < 2; ++i) {
            int row = row0 + i * 64;
            size_t ga = (size_t)(m0 + row) * KTOT + k0 + kcs * 8;
            size_t gb = (size_t)(n0 + row) * KTOT + k0 + kcs * 8;
            int loff = (i * 256 + tid) * 8;        // halves (linear dest)
            GLOAD_LDS16(Ahi + ga, sAh + loff);
            GLOAD_LDS16(Alo + ga, sAl + loff);
            GLOAD_LDS16(Bhi + gb, sBh + loff);
            GLOAD_LDS16(Blo + gb, sBl + loff);
        }
        __syncthreads();
        f16x8 ah[4], al[4], bh[4], bl[4];
        #pragma unroll
        for (int i = 0; i < 4; ++i) {
            ah[i] = *(const f16x8*)&sAh[(wm + i * 16 + lr) * 32 + sw];
            al[i] = *(const f16x8*)&sAl[(wm + i * 16 + lr) * 32 + sw];
            bh[i] = *(const f16x8*)&sBh[(wn + i * 16 + lr) * 32 + sw];
            bl[i] = *(const f16x8*)&sBl[(wn + i * 16 + lr) * 32 + sw];
        }
        #pragma unroll
        for (int i = 0; i < 4; ++i)
            #pragma unroll
            for (int j = 0; j < 4; ++j) {
                acc[i][j] = __builtin_amdgcn_mfma_f32_16x16x32_f16(ah[i], bh[j], acc[i][j], 0, 0, 0);
                acc[i][j] = __builtin_amdgcn_mfma_f32_16x16x32_f16(ah[i], bl[j], acc[i][j], 0, 0, 0);
                acc[i][j] = __builtin_amdgcn_mfma_f32_16x16x32_f16(al[i], bh[j], acc[i][j], 0, 0, 0);
            }
        __syncthreads();
    }
    #pragma unroll
    for (int i = 0; i < 4; ++i)
        #pragma unroll
        for (int j = 0; j < 4; ++j) {
            int gcol = n0 + wn + j * 16 + lr;
            float bv = bi[gcol];
            #pragma unroll
            for (int r = 0; r < 4; ++r) {
                int grow = m0 + wm + i * 16 + lq * 4 + r;
                P[(size_t)grow * SIXH + gcol] = acc[i][j][r] + bv;
            }
        }
}

// ================= persistent fused timestep loop (cooperative launch) =================
// R3 structure (verified best). New: all cross-WG stores are NON-TEMPORAL so the
// barrier release's per-XCD L2 writeback (the hypothesized ~20us/sync cost) is
// near-empty. pred reads Wo in original [k][C] layout (coalesced across classes).
__global__ __launch_bounds__(256, 1) void fused_loop(
    const float* __restrict__ P,
    const float* __restrict__ Etab,
    const float* __restrict__ bs,
    const _Float16* __restrict__ WsThi,
    const _Float16* __restrict__ WsTlo,
    _Float16* __restrict__ hhi,
    _Float16* __restrict__ hlo,
    float* __restrict__ ps,
    const float* __restrict__ Wo,
    const float* __restrict__ bo,
    const int* __restrict__ labels,
    float* __restrict__ dists,
    float* __restrict__ comms,
    int* bar)
{
    __shared__ __align__(16) _Float16 sBh[COLS * H];   // 64 KB, XOR-swizzled
    __shared__ __align__(16) _Float16 sBl[COLS * H];   // 64 KB
    __shared__ __align__(16) float hs[H];              // 4 KB (h_new row for pred)
    __shared__ float vals[8];
    __shared__ int   idxs[8];
    __shared__ int   s_eidx;

    const int wg  = blockIdx.x;
    const int tid = threadIdx.x;
    const int n0  = wg * COLS;
    const int lane = tid & 63, w = tid >> 6;
    const int lr = lane & 15, lq = lane >> 4;

    // ---- stage Ws slice into LDS, swizzled: granule byte ^= (col&7)<<4 ----
    for (int gi = tid; gi < COLS * (H / 8); gi += 256) {
        int col = gi >> 7;          // 128 granules of 16B per col
        int kg  = gi & 127;
        int dst = (col * (H * 2) + kg * 16) ^ ((col & 7) << 4);   // bytes
        *(f16x8*)((char*)sBh + dst) = *(const f16x8*)&WsThi[(size_t)(n0 + col) * H + kg * 8];
        *(f16x8*)((char*)sBl + dst) = *(const f16x8*)&WsTlo[(size_t)(n0 + col) * H + kg * 8];
    }

    float creg[4] = {0.f, 0.f, 0.f, 0.f};   // c-state, j = jj*256 + tid
    float bsr[4][5];
    if (wg < B) {
        #pragma unroll
        for (int jj = 0; jj < 4; ++jj)
            #pragma unroll
            for (int k = 0; k < 5; ++k)
                bsr[jj][k] = bs[k * H + jj * 256 + tid];
    }
    if (tid == 0) s_eidx = 0;
    __syncthreads();     // local staging done; cross-WG inputs are stream-ordered

    const int mrow0 = w * 32;
    int bval = 0;

    for (int t = 0; t < T; ++t) {
        int eidx_cur = s_eidx;     // feedback embedding index for this step

        // ---------- phase 1: ps[:, n0:n0+32] = (h) @ Ws-slice, fp16x3 ----------
        f32x4 acc[2][2];
        #pragma unroll
        for (int i = 0; i < 2; ++i)
            #pragma unroll
            for (int j = 0; j < 2; ++j)
                acc[i][j] = (f32x4){0.f, 0.f, 0.f, 0.f};

        #pragma unroll 8
        for (int k0 = 0; k0 < H; k0 += 32) {
            f16x8 ah[2], al[2], bh[2], bl[2];
            #pragma unroll
            for (int i = 0; i < 2; ++i) {
                size_t ho = (size_t)(mrow0 + i * 16 + lr) * H + k0 + lq * 8;
                ah[i] = *(const f16x8*)&hhi[ho];
                al[i] = *(const f16x8*)&hlo[ho];
            }
            #pragma unroll
            for (int j = 0; j < 2; ++j) {
                int col = j * 16 + lr;
                int off = (col * (H * 2) + (k0 + lq * 8) * 2) ^ ((col & 7) << 4);
                bh[j] = *(const f16x8*)((const char*)sBh + off);
                bl[j] = *(const f16x8*)((const char*)sBl + off);
            }
            #pragma unroll
            for (int i = 0; i < 2; ++i)
                #pragma unroll
                for (int j = 0; j < 2; ++j) {
                    acc[i][j] = __builtin_amdgcn_mfma_f32_16x16x32_f16(ah[i], bh[j], acc[i][j], 0, 0, 0);
                    acc[i][j] = __builtin_amdgcn_mfma_f32_16x16x32_f16(ah[i], bl[j], acc[i][j], 0, 0, 0);
                    acc[i][j] = __builtin_amdgcn_mfma_f32_16x16x32_f16(al[i], bh[j], acc[i][j], 0, 0, 0);
                }
        }
        #pragma unroll
        for (int i = 0; i < 2; ++i)
            #pragma unroll
            for (int j = 0; j < 2; ++j)
                #pragma unroll
                for (int r = 0; r < 4; ++r)
                    __builtin_nontemporal_store(acc[i][j][r],
                        &ps[(size_t)(mrow0 + i * 16 + lq * 4 + r) * FIVEH + n0 + j * 16 + lr]);

        // ---- T14 prefetch: P-row (cold HBM) + Etab-row into regs; latency hides
        // under barrier arrival/poll. Independent of ps/h, so legal pre-barrier. ----
        float pf[4][6], pe[4][6];
        if (wg < B) {
            const float* prow = P + (size_t)(t * B + wg) * SIXH;
            const float* erow = Etab + (size_t)eidx_cur * SIXH;
            #pragma unroll
            for (int jj = 0; jj < 4; ++jj)
                #pragma unroll
                for (int k = 0; k < 6; ++k) {
                    pf[jj][k] = prow[k * H + jj * 256 + tid];
                    pe[jj][k] = erow[k * H + jj * 256 + tid];
                }
        }

        ++bval; gbar(bar, tid, bval);

        // ---------- phase 2: gate + pred + argmax for b = wg ----------
        if (wg < B) {
            const int b = wg;
            const float* psr = ps + (size_t)b * FIVEH;
            #pragma unroll
            for (int jj = 0; jj < 4; ++jj) {
                int j = jj * 256 + tid;
                float gv[5];
                #pragma unroll
                for (int k = 0; k < 5; ++k)
                    gv[k] = pf[jj][k] + pe[jj][k] + psr[k * H + j] + bsr[jj][k];
                float pi5 = pf[jj][5] + pe[jj][5];
                float ig = 1.f / (1.f + expf(-gv[0]));
                float fg = 1.f / (1.f + expf(-gv[1]));
                float mi = tanhf(gv[2]);
                float og = 1.f / (1.f + expf(-gv[3]));
                float hw = 1.f / (1.f + expf(-gv[4]));
                float cn = ig * mi + fg * creg[jj];
                float out = og * tanhf(cn);
                float hn = hw * out + (1.f - hw) * pi5;
                creg[jj] = cn;
                hs[j] = hn;
                _Float16 hh = (_Float16)hn;
                __builtin_nontemporal_store(hh, &hhi[(size_t)b * H + j]);
                __builtin_nontemporal_store((_Float16)(hn - (float)hh), &hlo[(size_t)b * H + j]);
            }
            __syncthreads();
            float predv = 0.f;
            if (tid < C) {
                predv = bo[tid];
                const float* wp = Wo + tid;
                #pragma unroll 8
                for (int k = 0; k < H; ++k)
                    predv = fmaf(hs[k], wp[(size_t)k * C], predv);   // coalesced across classes
                __builtin_nontemporal_store(predv, &dists[(size_t)(t * B + b) * C + tid]);
            }
            // wave-level argmax (lowest index wins ties), then 4-way combine
            float av = (tid >= 1 && tid < C) ? predv : -1e30f;
            int   ai = tid;
            #pragma unroll
            for (int s = 32; s > 0; s >>= 1) {
                float v2 = __shfl_down(av, s, 64);
                int   i2 = __shfl_down(ai, s, 64);
                if (v2 > av || (v2 == av && i2 < ai)) { av = v2; ai = i2; }
            }
            if (lane == 0) { vals[w] = av; idxs[w] = ai; }
            __syncthreads();
            if (tid == 0) {
                float bv2 = vals[0]; int bi2 = idxs[0];
                #pragma unroll
                for (int k = 1; k < 4; ++k)
                    if (vals[k] > bv2 || (vals[k] == bv2 && idxs[k] < bi2)) {
                        bv2 = vals[k]; bi2 = idxs[k];
                    }
                int lt = labels[t * B + b];
                int comm = (lt == 0) ? bi2 : lt;
                __builtin_nontemporal_store((float)comm, &comms[t * B + b]);
                s_eidx = comm + 1;
            }
        }
        ++bval; gbar(bar, tid, bval);
    }
}

// ================= fallback per-timestep kernels (used only if coop launch fails) =====
__global__ __launch_bounds__(256) void ps_mfma(
    const _Float16* __restrict__ Ahi, const _Float16* __restrict__ Alo,
    const _Float16* __restrict__ Bhi, const _Float16* __restrict__ Blo,
    float* __restrict__ ps)
{
    __shared__ __align__(16) _Float16 sAh[64 * 32];
    __shared__ __align__(16) _Float16 sAl[64 * 32];
    __shared__ __align__(16) _Float16 sBh[64 * 32];
    __shared__ __align__(16) _Float16 sBl[64 * 32];
    const int tid = threadIdx.x;
    const int n0 = blockIdx.x * 64;
    const int m0 = blockIdx.y * 64;
    const int lane = tid & 63, w = tid >> 6;
    const int wm = (w >> 1) * 32, wn = (w & 1) * 32;
    const int lr = lane & 15, lq = lane >> 4;

    f32x4 acc[2][2];
    #pragma unroll
    for (int i = 0; i < 2; ++i)
        #pragma unroll
        for (int j = 0; j < 2; ++j)
            acc[i][j] = (f32x4){0.f, 0.f, 0.f, 0.f};

    const int row = tid >> 2;
    const int kc = tid & 3;

    for (int k0 = 0; k0 < H; k0 += 32) {
        size_t ga = (size_t)(m0 + row) * H + k0 + kc * 8;
        size_t gb = (size_t)(n0 + row) * H + k0 + kc * 8;
        int loff = tid * 8;
        GLOAD_LDS16(Ahi + ga, sAh + loff);
        GLOAD_LDS16(Alo + ga, sAl + loff);
        GLOAD_LDS16(Bhi + gb, sBh + loff);
        GLOAD_LDS16(Blo + gb, sBl + loff);
        __syncthreads();
        f16x8 ah[2], al[2], bh[2], bl[2];
        #pragma unroll
        for (int i = 0; i < 2; ++i) {
            ah[i] = *(const f16x8*)&sAh[(wm + i * 16 + lr) * 32 + lq * 8];
            al[i] = *(const f16x8*)&sAl[(wm + i * 16 + lr) * 32 + lq * 8];
            bh[i] = *(const f16x8*)&sBh[(wn + i * 16 + lr) * 32 + lq * 8];
            bl[i] = *(const f16x8*)&sBl[(wn + i * 16 + lr) * 32 + lq * 8];
        }
        #pragma unroll
        for (int i = 0; i < 2; ++i)
            #pragma unroll
            for (int j = 0; j < 2; ++j) {
                acc[i][j] = __builtin_amdgcn_mfma_f32_16x16x32_f16(ah[i], bh[j], acc[i][j], 0, 0, 0);
                acc[i][j] = __builtin_amdgcn_mfma_f32_16x16x32_f16(ah[i], bl[j], acc[i][j], 0, 0, 0);
                acc[i][j] = __builtin_amdgcn_mfma_f32_16x16x32_f16(al[i], bh[j], acc[i][j], 0, 0, 0);
            }
        __syncthreads();
    }
    #pragma unroll
    for (int i = 0; i < 2; ++i)
        #pragma unroll
        for (int j = 0; j < 2; ++j) {
            int gcol = n0 + wn + j * 16 + lr;
            #pragma unroll
            for (int r = 0; r < 4; ++r) {
                int grow = m0 + wm + i * 16 + lq * 4 + r;
                ps[(size_t)grow * FIVEH + gcol] = acc[i][j][r];
            }
        }
}

__global__ void gate_kernel(const float* __restrict__ P,
                            const float* __restrict__ Etab,
                            const float* __restrict__ ps,
                            const float* __restrict__ bs,
                            const int* __restrict__ eidx,
                            float* __restrict__ h,
                            float* __restrict__ c,
                            _Float16* __restrict__ hhi,
                            _Float16* __restrict__ hlo,
                            int t) {
    int j = blockIdx.x * 256 + threadIdx.x;
    int b = blockIdx.y;
    const float* prow = P + (size_t)(t * B + b) * SIXH;
    const float* erow = Etab + (size_t)eidx[b] * SIXH;
    const float* psr  = ps + (size_t)b * FIVEH;
    float g[5];
    #pragma unroll
    for (int k = 0; k < 5; ++k) {
        int col = k * H + j;
        g[k] = prow[col] + erow[col] + psr[col] + bs[col];
    }
    float pi5 = prow[5 * H + j] + erow[5 * H + j];
    float ig = 1.f / (1.f + expf(-g[0]));
    float fg = 1.f / (1.f + expf(-g[1]));
    float mi = tanhf(g[2]);
    float og = 1.f / (1.f + expf(-g[3]));
    float hw = 1.f / (1.f + expf(-g[4]));
    float cv = c[b * H + j];
    float cn = ig * mi + fg * cv;
    float out = og * tanhf(cn);
    float hn = hw * out + (1.f - hw) * pi5;
    c[b * H + j] = cn;
    h[b * H + j] = hn;
    _Float16 hh = (_Float16)hn;
    hhi[b * H + j] = hh;
    hlo[b * H + j] = (_Float16)(hn - (float)hh);
}

__global__ void pred_kernel(const float* __restrict__ h,
                            const float* __restrict__ Wo,
                            const float* __restrict__ bo,
                            const int* __restrict__ labels,
                            float* __restrict__ dists,
                            float* __restrict__ comms,
                            int* __restrict__ eidx,
                            int t) {
    __shared__ float hsb[H];
    __shared__ float vals[256];
    __shared__ int   idxs[256];
    int tid = threadIdx.x;
    int b = blockIdx.x;
    for (int i = tid; i < H / 4; i += 256)
        *(float4*)&hsb[i * 4] = *(const float4*)&h[b * H + i * 4];
    __syncthreads();
    float pred = 0.f;
    if (tid < C) {
        pred = bo[tid];
        #pragma unroll 8
        for (int k = 0; k < H; ++k)
            pred = fmaf(hsb[k], Wo[k * C + tid], pred);
        dists[(size_t)(t * B + b) * C + tid] = pred;
    }
    vals[tid] = (tid >= 1 && tid < C) ? pred : -1e30f;
    idxs[tid] = tid;
    __syncthreads();
    for (int s = 128; s > 0; s >>= 1) {
        if (tid < s) {
            float v2 = vals[tid + s];
            int   i2 = idxs[tid + s];
            if (v2 > vals[tid] || (v2 == vals[tid] && i2 < idxs[tid])) {
                vals[tid] = v2;
                idxs[tid] = i2;
            }
        }
        __syncthreads();
    }
    if (tid == 0) {
        int nzp = idxs[0];
        int lt = labels[t * B + b];
        int comm = (lt == 0) ? nzp : lt;
        comms[t * B + b] = (float)comm;
        eidx[b] = comm + 1;
    }
}

extern "C" void kernel_launch(void* const* d_in, const int* in_sizes, int n_in,
                              void* d_out, int out_size, void* d_ws, size_t ws_size,
                              hipStream_t stream) {
    const float* X      = (const float*)d_in[0];
    const int*   labels = (const int*)  d_in[1];
    const float* embed  = (const float*)d_in[2];
    const float* Wi     = (const float*)d_in[3];
    const float* bi     = (const float*)d_in[4];
    const float* Ws     = (const float*)d_in[5];
    const float* bs     = (const float*)d_in[6];
    const float* Wo     = (const float*)d_in[7];
    const float* bo     = (const float*)d_in[8];

    // Workspace layout identical to R3 (verified-running footprint).
    char* w = (char*)d_ws;
    float* P      = (float*)w;              w += (size_t)T * B * SIXH * 4;      // 100.7 MB
    float* Etab   = (float*)w;              w += (size_t)NEMB * SIXH * 4;       //   3.7 MB
    float* ps     = (float*)w;              w += (size_t)B * FIVEH * 4;         //   2.6 MB
    float* h      = (float*)w;              w += (size_t)B * H * 4;
    float* c      = (float*)w;              w += (size_t)B * H * 4;
    _Float16* hhi = (_Float16*)w;           w += (size_t)B * H * 2;
    _Float16* hlo = (_Float16*)w;           w += (size_t)B * H * 2;
    int* eidx     = (int*)w;                w += 512;
    int* bar      = (int*)w;                w += 16384;                          // NWG*16 flags (padded)
    _Float16* Xhi = (_Float16*)w;           w += (size_t)T * B * KTOT * 2;      //  16.8 MB
    _Float16* Xlo = (_Float16*)w;           w += (size_t)T * B * KTOT * 2;
    _Float16* WiThi = (_Float16*)w;         w += (size_t)SIXH * KTOT * 2;       //  25.2 MB
    _Float16* WiTlo = (_Float16*)w;         w += (size_t)SIXH * KTOT * 2;
    _Float16* WsThi = (_Float16*)w;         w += (size_t)FIVEH * H * 2;         //  10.5 MB
    _Float16* WsTlo = (_Float16*)w;         w += (size_t)FIVEH * H * 2;

    float* dists = (float*)d_out;
    float* comms = dists + (size_t)T * B * C;

    init_kernel<<<512, 256, 0, stream>>>(h, c, hhi, hlo, eidx, bar);
    cvt_x<<<(T * B * KTOT) / (256 * 4), 256, 0, stream>>>(X, Xhi, Xlo);
    cvt_wT<KTOT, SIXH><<<dim3(SIXH / 32, KTOT / 32), 256, 0, stream>>>(Wi, WiThi, WiTlo);
    cvt_wT<H, FIVEH><<<dim3(FIVEH / 32, H / 32), 256, 0, stream>>>(Ws, WsThi, WsTlo);
    etab_kernel<<<dim3(SIXH / 256, NEMB), 256, 0, stream>>>(embed, Wi, Etab);
    big_gemm_mfma<<<dim3(SIXH / 128, (T * B) / 128), 256, 0, stream>>>(Xhi, Xlo, WiThi, WiTlo, bi, P);

    void* args[] = {(void*)&P, (void*)&Etab, (void*)&bs, (void*)&WsThi, (void*)&WsTlo,
                    (void*)&hhi, (void*)&hlo, (void*)&ps, (void*)&Wo, (void*)&bo,
                    (void*)&labels, (void*)&dists, (void*)&comms, (void*)&bar};
    hipError_t err = hipLaunchCooperativeKernel((void*)fused_loop, dim3(NWG), dim3(256),
                                                args, 0, stream);
    if (err != hipSuccess) {
        // fallback: original per-timestep loop
        for (int t = 0; t < T; ++t) {
            ps_mfma<<<dim3(FIVEH / 64, B / 64), 256, 0, stream>>>(hhi, hlo, WsThi, WsTlo, ps);
            gate_kernel<<<dim3(H / 256, B), 256, 0, stream>>>(P, Etab, ps, bs, eidx, h, c, hhi, hlo, t);
            pred_kernel<<<B, 256, 0, stream>>>(h, Wo, bo, labels, dists, comms, eidx, t);
        }
    }
}

// Round 9
// 2442.784 us; speedup vs baseline: 2.5191x; 1.0356x over previous
//
#include <hip/hip_runtime.h>
#include <math.h>

#define H    1024
#define C    151
#define E    200
#define DIN  2048
#define T    32
#define B    128
#define SIXH  (6*H)   // 6144
#define FIVEH (5*H)   // 5120
#define KTOT  DIN     // 2048
#define NEMB  (C+1)   // 152
#define NWG   160     // persistent blocks; 160*32 = 5120 cols
#define COLS  32      // ps columns per WG
#define GUARD (1 << 20)   // spin bailout: bounded wrong-answer beats container-killing hang

typedef _Float16 f16x8 __attribute__((ext_vector_type(8)));
typedef _Float16 f16x4 __attribute__((ext_vector_type(4)));
typedef float    f32x4 __attribute__((ext_vector_type(4)));

#define GLOAD_LDS16(g, l) __builtin_amdgcn_global_load_lds( \
    (const __attribute__((address_space(1))) unsigned int*)(g), \
    (__attribute__((address_space(3))) unsigned int*)(l), 16, 0, 0)

// ---- flag-array grid barrier (verified best: R3, fused_loop 1902us) ----
// Session evidence (R1-R8): single contended counter ~35us/sync (160 serialized
// cross-XCD RMWs); this flag-array form ~23us/sync; epoch/dataflow/NT variants
// all >= it. The residual ~23us is the cross-XCD coherence round-trip + fence
// cost itself — invariant to poll topology and dirty-L2 volume. This is a
// latency floor of agent-scope sync on MI355X, not a memory/compute roofline.
__device__ __forceinline__ void gbar(int* slots, int tid, int val) {
    __syncthreads();   // WG stores drained (per-wave vmcnt) before release RMW
    if (tid == 0)
        __hip_atomic_fetch_add(&slots[blockIdx.x * 16], 1,
                               __ATOMIC_ACQ_REL, __HIP_MEMORY_SCOPE_AGENT);
    int ok, guard = 0;
    do {
        int v = val;
        if (tid < NWG)
            v = __hip_atomic_load(&slots[tid * 16],
                                  __ATOMIC_RELAXED, __HIP_MEMORY_SCOPE_AGENT);
        ok = __syncthreads_and(v >= val);
        if (!ok) __builtin_amdgcn_s_sleep(1);
    } while (!ok && ++guard < GUARD);
    __builtin_amdgcn_fence(__ATOMIC_ACQUIRE, "agent");
}

// ---------------- init: zero h, c, hhi, hlo, eidx, barrier slots ----------------
__global__ void init_kernel(float* h, float* c, _Float16* hhi, _Float16* hlo,
                            int* eidx, int* bar) {
    int i = blockIdx.x * blockDim.x + threadIdx.x;
    if (i < B * H) {
        h[i] = 0.f; c[i] = 0.f;
        hhi[i] = (_Float16)0.f; hlo[i] = (_Float16)0.f;
    }
    if (i < B) eidx[i] = 0;
    if (i < NWG * 16) bar[i] = 0;
}

// ---------------- X [4096][2048] fp32 -> hi/lo fp16 (same layout) ----------------
__global__ void cvt_x(const float* __restrict__ X, _Float16* __restrict__ hi,
                      _Float16* __restrict__ lo) {
    size_t i = ((size_t)blockIdx.x * 256 + threadIdx.x) * 4;
    float4 v = *(const float4*)(X + i);
    f16x4 h, l;
    h.x = (_Float16)v.x; l.x = (_Float16)(v.x - (float)h.x);
    h.y = (_Float16)v.y; l.y = (_Float16)(v.y - (float)h.y);
    h.z = (_Float16)v.z; l.z = (_Float16)(v.z - (float)h.z);
    h.w = (_Float16)v.w; l.w = (_Float16)(v.w - (float)h.w);
    *(f16x4*)(hi + i) = h;
    *(f16x4*)(lo + i) = l;
}

// ---------------- W [KR][NC] fp32 -> out [NC][KR] hi/lo fp16 (transposed) ----------------
template<int KR, int NC>
__global__ void cvt_wT(const float* __restrict__ W, _Float16* __restrict__ hi,
                       _Float16* __restrict__ lo) {
    __shared__ float tile[32][33];
    int n0 = blockIdx.x * 32, k0 = blockIdx.y * 32;
    int tx = threadIdx.x & 31, ty = threadIdx.x >> 5;   // ty 0..7
    #pragma unroll
    for (int i = 0; i < 4; ++i) {
        int k = ty + i * 8;
        tile[k][tx] = W[(size_t)(k0 + k) * NC + n0 + tx];
    }
    __syncthreads();
    #pragma unroll
    for (int i = 0; i < 4; ++i) {
        int n = ty + i * 8;
        float v = tile[tx][n];              // = W[k0+tx][n0+n]
        _Float16 h = (_Float16)v;
        size_t o = (size_t)(n0 + n) * KR + k0 + tx;
        hi[o] = h;
        lo[o] = (_Float16)(v - (float)h);
    }
}

// ---------------- Wo [H][C] fp32 -> WoT [C][H] ----------------
__global__ void cvt_woT(const float* __restrict__ Wo, float* __restrict__ WoT) {
    int k = blockIdx.x * 256 + threadIdx.x;  // 0..H-1
    for (int c = 0; c < C; ++c)
        WoT[(size_t)c * H + k] = Wo[(size_t)k * C + c];
}

// ---------------- Etab[k][n] = sum_e embed[k][e] * Wi[DIN+e][n]  (fp32) ----------------
__global__ void etab_kernel(const float* __restrict__ embed,
                            const float* __restrict__ Wi,
                            float* __restrict__ Etab) {
    int n = blockIdx.x * 256 + threadIdx.x;
    int k = blockIdx.y;
    const float* wp = Wi + (size_t)DIN * SIXH + n;
    const float* ep = embed + k * E;
    float acc = 0.f;
    #pragma unroll 8
    for (int e = 0; e < E; ++e)
        acc = fmaf(ep[e], wp[(size_t)e * SIXH], acc);
    Etab[(size_t)k * SIXH + n] = acc;
}

// ---------------- P = X @ Wi_x + bi, fp16x3 MFMA. tile 128x128, 4 waves x 64x64 ----------
__global__ __launch_bounds__(256) void big_gemm_mfma(
    const _Float16* __restrict__ Ahi, const _Float16* __restrict__ Alo,
    const _Float16* __restrict__ Bhi, const _Float16* __restrict__ Blo,
    const float* __restrict__ bi, float* __restrict__ P)
{
    __shared__ __align__(16) _Float16 sAh[128 * 32];
    __shared__ __align__(16) _Float16 sAl[128 * 32];
    __shared__ __align__(16) _Float16 sBh[128 * 32];
    __shared__ __align__(16) _Float16 sBl[128 * 32];
    const int tid = threadIdx.x;
    const int n0 = blockIdx.x * 128;
    const int m0 = blockIdx.y * 128;
    const int lane = tid & 63, w = tid >> 6;
    const int wm = (w >> 1) * 64, wn = (w & 1) * 64;
    const int lr = lane & 15, lq = lane >> 4;

    f32x4 acc[4][4];
    #pragma unroll
    for (int i = 0; i < 4; ++i)
        #pragma unroll
        for (int j = 0; j < 4; ++j)
            acc[i][j] = (f32x4){0.f, 0.f, 0.f, 0.f};

    const int row0 = tid >> 2;        // 0..63
    const int kc = tid & 3;
    const int kcs = kc ^ ((row0 >> 1) & 3);   // swizzled source chunk
    const int sw = (lq ^ ((lr >> 1) & 3)) * 8; // swizzled read slot (halves)

    for (int k0 = 0; k0 < KTOT; k0 += 32) {
        #pragma unroll
        for (int i = 0; i < 2; ++i) {
            int row = row0 + i * 64;
            size_t ga = (size_t)(m0 + row) * KTOT + k0 + kcs * 8;
            size_t gb = (size_t)(n0 + row) * KTOT + k0 + kcs * 8;
            int loff = (i * 256 + tid) * 8;        // halves (linear dest)
            GLOAD_LDS16(Ahi + ga, sAh + loff);
            GLOAD_LDS16(Alo + ga, sAl + loff);
            GLOAD_LDS16(Bhi + gb, sBh + loff);
            GLOAD_LDS16(Blo + gb, sBl + loff);
        }
        __syncthreads();
        f16x8 ah[4], al[4], bh[4], bl[4];
        #pragma unroll
        for (int i = 0; i < 4; ++i) {
            ah[i] = *(const f16x8*)&sAh[(wm + i * 16 + lr) * 32 + sw];
            al[i] = *(const f16x8*)&sAl[(wm + i * 16 + lr) * 32 + sw];
            bh[i] = *(const f16x8*)&sBh[(wn + i * 16 + lr) * 32 + sw];
            bl[i] = *(const f16x8*)&sBl[(wn + i * 16 + lr) * 32 + sw];
        }
        #pragma unroll
        for (int i = 0; i < 4; ++i)
            #pragma unroll
            for (int j = 0; j < 4; ++j) {
                acc[i][j] = __builtin_amdgcn_mfma_f32_16x16x32_f16(ah[i], bh[j], acc[i][j], 0, 0, 0);
                acc[i][j] = __builtin_amdgcn_mfma_f32_16x16x32_f16(ah[i], bl[j], acc[i][j], 0, 0, 0);
                acc[i][j] = __builtin_amdgcn_mfma_f32_16x16x32_f16(al[i], bh[j], acc[i][j], 0, 0, 0);
            }
        __syncthreads();
    }
    #pragma unroll
    for (int i = 0; i < 4; ++i)
        #pragma unroll
        for (int j = 0; j < 4; ++j) {
            int gcol = n0 + wn + j * 16 + lr;
            float bv = bi[gcol];
            #pragma unroll
            for (int r = 0; r < 4; ++r) {
                int grow = m0 + wm + i * 16 + lq * 4 + r;
                P[(size_t)grow * SIXH + gcol] = acc[i][j][r] + bv;
            }
        }
}

// ================= persistent fused timestep loop (cooperative launch) =================
// Verified-best configuration (R3): Ws-slice LDS-resident (loaded once), c-state
// in registers, T14 P/Etab prefetch under barrier 1, two flag-array barriers/step.
__global__ __launch_bounds__(256, 1) void fused_loop(
    const float* __restrict__ P,
    const float* __restrict__ Etab,
    const float* __restrict__ bs,
    const _Float16* __restrict__ WsThi,
    const _Float16* __restrict__ WsTlo,
    _Float16* __restrict__ hhi,
    _Float16* __restrict__ hlo,
    float* __restrict__ ps,
    const float* __restrict__ WoT,
    const float* __restrict__ bo,
    const int* __restrict__ labels,
    float* __restrict__ dists,
    float* __restrict__ comms,
    int* bar)
{
    __shared__ __align__(16) _Float16 sBh[COLS * H];   // 64 KB, XOR-swizzled
    __shared__ __align__(16) _Float16 sBl[COLS * H];   // 64 KB
    __shared__ __align__(16) float hs[H];              // 4 KB (h_new row for pred)
    __shared__ float vals[256];
    __shared__ int   idxs[256];
    __shared__ int   s_eidx;

    const int wg  = blockIdx.x;
    const int tid = threadIdx.x;
    const int n0  = wg * COLS;
    const int lane = tid & 63, w = tid >> 6;
    const int lr = lane & 15, lq = lane >> 4;

    // ---- stage Ws slice into LDS, swizzled: granule byte ^= (col&7)<<4 ----
    for (int gi = tid; gi < COLS * (H / 8); gi += 256) {
        int col = gi >> 7;          // 128 granules of 16B per col
        int kg  = gi & 127;
        int dst = (col * (H * 2) + kg * 16) ^ ((col & 7) << 4);   // bytes
        *(f16x8*)((char*)sBh + dst) = *(const f16x8*)&WsThi[(size_t)(n0 + col) * H + kg * 8];
        *(f16x8*)((char*)sBl + dst) = *(const f16x8*)&WsTlo[(size_t)(n0 + col) * H + kg * 8];
    }

    float creg[4] = {0.f, 0.f, 0.f, 0.f};   // c-state, j = jj*256 + tid
    float bsr[4][5];
    if (wg < B) {
        #pragma unroll
        for (int jj = 0; jj < 4; ++jj)
            #pragma unroll
            for (int k = 0; k < 5; ++k)
                bsr[jj][k] = bs[k * H + jj * 256 + tid];
    }
    if (tid == 0) s_eidx = 0;
    __syncthreads();     // local staging done; cross-WG inputs are stream-ordered

    const int mrow0 = w * 32;
    int bval = 0;

    for (int t = 0; t < T; ++t) {
        int eidx_cur = s_eidx;     // feedback embedding index for this step

        // ---------- phase 1: ps[:, n0:n0+32] = (h) @ Ws-slice, fp16x3 ----------
        f32x4 acc[2][2];
        #pragma unroll
        for (int i = 0; i < 2; ++i)
            #pragma unroll
            for (int j = 0; j < 2; ++j)
                acc[i][j] = (f32x4){0.f, 0.f, 0.f, 0.f};

        #pragma unroll 4
        for (int k0 = 0; k0 < H; k0 += 32) {
            f16x8 ah[2], al[2], bh[2], bl[2];
            #pragma unroll
            for (int i = 0; i < 2; ++i) {
                size_t ho = (size_t)(mrow0 + i * 16 + lr) * H + k0 + lq * 8;
                ah[i] = *(const f16x8*)&hhi[ho];
                al[i] = *(const f16x8*)&hlo[ho];
            }
            #pragma unroll
            for (int j = 0; j < 2; ++j) {
                int col = j * 16 + lr;
                int off = (col * (H * 2) + (k0 + lq * 8) * 2) ^ ((col & 7) << 4);
                bh[j] = *(const f16x8*)((const char*)sBh + off);
                bl[j] = *(const f16x8*)((const char*)sBl + off);
            }
            #pragma unroll
            for (int i = 0; i < 2; ++i)
                #pragma unroll
                for (int j = 0; j < 2; ++j) {
                    acc[i][j] = __builtin_amdgcn_mfma_f32_16x16x32_f16(ah[i], bh[j], acc[i][j], 0, 0, 0);
                    acc[i][j] = __builtin_amdgcn_mfma_f32_16x16x32_f16(ah[i], bl[j], acc[i][j], 0, 0, 0);
                    acc[i][j] = __builtin_amdgcn_mfma_f32_16x16x32_f16(al[i], bh[j], acc[i][j], 0, 0, 0);
                }
        }
        #pragma unroll
        for (int i = 0; i < 2; ++i)
            #pragma unroll
            for (int j = 0; j < 2; ++j)
                #pragma unroll
                for (int r = 0; r < 4; ++r)
                    ps[(size_t)(mrow0 + i * 16 + lq * 4 + r) * FIVEH + n0 + j * 16 + lr] = acc[i][j][r];

        // ---- T14 prefetch: P-row (cold HBM) + Etab-row into regs; latency hides
        // under barrier arrival/poll. Independent of ps/h, so legal pre-barrier. ----
        float pf[4][6], pe[4][6];
        if (wg < B) {
            const float* prow = P + (size_t)(t * B + wg) * SIXH;
            const float* erow = Etab + (size_t)eidx_cur * SIXH;
            #pragma unroll
            for (int jj = 0; jj < 4; ++jj)
                #pragma unroll
                for (int k = 0; k < 6; ++k) {
                    pf[jj][k] = prow[k * H + jj * 256 + tid];
                    pe[jj][k] = erow[k * H + jj * 256 + tid];
                }
        }

        ++bval; gbar(bar, tid, bval);

        // ---------- phase 2: gate + pred + argmax for b = wg ----------
        if (wg < B) {
            const int b = wg;
            const float* psr = ps + (size_t)b * FIVEH;
            #pragma unroll
            for (int jj = 0; jj < 4; ++jj) {
                int j = jj * 256 + tid;
                float gv[5];
                #pragma unroll
                for (int k = 0; k < 5; ++k)
                    gv[k] = pf[jj][k] + pe[jj][k] + psr[k * H + j] + bsr[jj][k];
                float pi5 = pf[jj][5] + pe[jj][5];
                float ig = 1.f / (1.f + expf(-gv[0]));
                float fg = 1.f / (1.f + expf(-gv[1]));
                float mi = tanhf(gv[2]);
                float og = 1.f / (1.f + expf(-gv[3]));
                float hw = 1.f / (1.f + expf(-gv[4]));
                float cn = ig * mi + fg * creg[jj];
                float out = og * tanhf(cn);
                float hn = hw * out + (1.f - hw) * pi5;
                creg[jj] = cn;
                hs[j] = hn;
                _Float16 hh = (_Float16)hn;
                hhi[(size_t)b * H + j] = hh;
                hlo[(size_t)b * H + j] = (_Float16)(hn - (float)hh);
            }
            __syncthreads();
            float predv = 0.f;
            if (tid < C) {
                const float* wp = WoT + (size_t)tid * H;
                float a0 = bo[tid], a1 = 0.f, a2 = 0.f, a3 = 0.f;
                #pragma unroll 4
                for (int k = 0; k < H; k += 4) {
                    float4 w4 = *(const float4*)&wp[k];
                    float4 h4 = *(const float4*)&hs[k];
                    a0 = fmaf(h4.x, w4.x, a0);
                    a1 = fmaf(h4.y, w4.y, a1);
                    a2 = fmaf(h4.z, w4.z, a2);
                    a3 = fmaf(h4.w, w4.w, a3);
                }
                predv = (a0 + a1) + (a2 + a3);
                dists[(size_t)(t * B + b) * C + tid] = predv;
            }
            vals[tid] = (tid >= 1 && tid < C) ? predv : -1e30f;
            idxs[tid] = tid;
            __syncthreads();
            for (int s = 128; s > 0; s >>= 1) {
                if (tid < s) {
                    float v2 = vals[tid + s];
                    int   i2 = idxs[tid + s];
                    if (v2 > vals[tid] || (v2 == vals[tid] && i2 < idxs[tid])) {
                        vals[tid] = v2;
                        idxs[tid] = i2;
                    }
                }
                __syncthreads();
            }
            if (tid == 0) {
                int nzp = idxs[0];
                int lt = labels[t * B + b];
                int comm = (lt == 0) ? nzp : lt;
                comms[t * B + b] = (float)comm;
                s_eidx = comm + 1;
            }
        }
        ++bval; gbar(bar, tid, bval);
    }
}

// ================= fallback per-timestep kernels (used only if coop launch fails) =====
__global__ __launch_bounds__(256) void ps_mfma(
    const _Float16* __restrict__ Ahi, const _Float16* __restrict__ Alo,
    const _Float16* __restrict__ Bhi, const _Float16* __restrict__ Blo,
    float* __restrict__ ps)
{
    __shared__ __align__(16) _Float16 sAh[64 * 32];
    __shared__ __align__(16) _Float16 sAl[64 * 32];
    __shared__ __align__(16) _Float16 sBh[64 * 32];
    __shared__ __align__(16) _Float16 sBl[64 * 32];
    const int tid = threadIdx.x;
    const int n0 = blockIdx.x * 64;
    const int m0 = blockIdx.y * 64;
    const int lane = tid & 63, w = tid >> 6;
    const int wm = (w >> 1) * 32, wn = (w & 1) * 32;
    const int lr = lane & 15, lq = lane >> 4;

    f32x4 acc[2][2];
    #pragma unroll
    for (int i = 0; i < 2; ++i)
        #pragma unroll
        for (int j = 0; j < 2; ++j)
            acc[i][j] = (f32x4){0.f, 0.f, 0.f, 0.f};

    const int row = tid >> 2;
    const int kc = tid & 3;

    for (int k0 = 0; k0 < H; k0 += 32) {
        size_t ga = (size_t)(m0 + row) * H + k0 + kc * 8;
        size_t gb = (size_t)(n0 + row) * H + k0 + kc * 8;
        int loff = tid * 8;
        GLOAD_LDS16(Ahi + ga, sAh + loff);
        GLOAD_LDS16(Alo + ga, sAl + loff);
        GLOAD_LDS16(Bhi + gb, sBh + loff);
        GLOAD_LDS16(Blo + gb, sBl + loff);
        __syncthreads();
        f16x8 ah[2], al[2], bh[2], bl[2];
        #pragma unroll
        for (int i = 0; i < 2; ++i) {
            ah[i] = *(const f16x8*)&sAh[(wm + i * 16 + lr) * 32 + lq * 8];
            al[i] = *(const f16x8*)&sAl[(wm + i * 16 + lr) * 32 + lq * 8];
            bh[i] = *(const f16x8*)&sBh[(wn + i * 16 + lr) * 32 + lq * 8];
            bl[i] = *(const f16x8*)&sBl[(wn + i * 16 + lr) * 32 + lq * 8];
        }
        #pragma unroll
        for (int i = 0; i < 2; ++i)
            #pragma unroll
            for (int j = 0; j < 2; ++j) {
                acc[i][j] = __builtin_amdgcn_mfma_f32_16x16x32_f16(ah[i], bh[j], acc[i][j], 0, 0, 0);
                acc[i][j] = __builtin_amdgcn_mfma_f32_16x16x32_f16(ah[i], bl[j], acc[i][j], 0, 0, 0);
                acc[i][j] = __builtin_amdgcn_mfma_f32_16x16x32_f16(al[i], bh[j], acc[i][j], 0, 0, 0);
            }
        __syncthreads();
    }
    #pragma unroll
    for (int i = 0; i < 2; ++i)
        #pragma unroll
        for (int j = 0; j < 2; ++j) {
            int gcol = n0 + wn + j * 16 + lr;
            #pragma unroll
            for (int r = 0; r < 4; ++r) {
                int grow = m0 + wm + i * 16 + lq * 4 + r;
                ps[(size_t)grow * FIVEH + gcol] = acc[i][j][r];
            }
        }
}

__global__ void gate_kernel(const float* __restrict__ P,
                            const float* __restrict__ Etab,
                            const float* __restrict__ ps,
                            const float* __restrict__ bs,
                            const int* __restrict__ eidx,
                            float* __restrict__ h,
                            float* __restrict__ c,
                            _Float16* __restrict__ hhi,
                            _Float16* __restrict__ hlo,
                            int t) {
    int j = blockIdx.x * 256 + threadIdx.x;
    int b = blockIdx.y;
    const float* prow = P + (size_t)(t * B + b) * SIXH;
    const float* erow = Etab + (size_t)eidx[b] * SIXH;
    const float* psr  = ps + (size_t)b * FIVEH;
    float g[5];
    #pragma unroll
    for (int k = 0; k < 5; ++k) {
        int col = k * H + j;
        g[k] = prow[col] + erow[col] + psr[col] + bs[col];
    }
    float pi5 = prow[5 * H + j] + erow[5 * H + j];
    float ig = 1.f / (1.f + expf(-g[0]));
    float fg = 1.f / (1.f + expf(-g[1]));
    float mi = tanhf(g[2]);
    float og = 1.f / (1.f + expf(-g[3]));
    float hw = 1.f / (1.f + expf(-g[4]));
    float cv = c[b * H + j];
    float cn = ig * mi + fg * cv;
    float out = og * tanhf(cn);
    float hn = hw * out + (1.f - hw) * pi5;
    c[b * H + j] = cn;
    h[b * H + j] = hn;
    _Float16 hh = (_Float16)hn;
    hhi[b * H + j] = hh;
    hlo[b * H + j] = (_Float16)(hn - (float)hh);
}

__global__ void pred_kernel(const float* __restrict__ h,
                            const float* __restrict__ Wo,
                            const float* __restrict__ bo,
                            const int* __restrict__ labels,
                            float* __restrict__ dists,
                            float* __restrict__ comms,
                            int* __restrict__ eidx,
                            int t) {
    __shared__ float hsb[H];
    __shared__ float vals[256];
    __shared__ int   idxs[256];
    int tid = threadIdx.x;
    int b = blockIdx.x;
    for (int i = tid; i < H / 4; i += 256)
        *(float4*)&hsb[i * 4] = *(const float4*)&h[b * H + i * 4];
    __syncthreads();
    float pred = 0.f;
    if (tid < C) {
        pred = bo[tid];
        #pragma unroll 8
        for (int k = 0; k < H; ++k)
            pred = fmaf(hsb[k], Wo[k * C + tid], pred);
        dists[(size_t)(t * B + b) * C + tid] = pred;
    }
    vals[tid] = (tid >= 1 && tid < C) ? pred : -1e30f;
    idxs[tid] = tid;
    __syncthreads();
    for (int s = 128; s > 0; s >>= 1) {
        if (tid < s) {
            float v2 = vals[tid + s];
            int   i2 = idxs[tid + s];
            if (v2 > vals[tid] || (v2 == vals[tid] && i2 < idxs[tid])) {
                vals[tid] = v2;
                idxs[tid] = i2;
            }
        }
        __syncthreads();
    }
    if (tid == 0) {
        int nzp = idxs[0];
        int lt = labels[t * B + b];
        int comm = (lt == 0) ? nzp : lt;
        comms[t * B + b] = (float)comm;
        eidx[b] = comm + 1;
    }
}

extern "C" void kernel_launch(void* const* d_in, const int* in_sizes, int n_in,
                              void* d_out, int out_size, void* d_ws, size_t ws_size,
                              hipStream_t stream) {
    const float* X      = (const float*)d_in[0];
    const int*   labels = (const int*)  d_in[1];
    const float* embed  = (const float*)d_in[2];
    const float* Wi     = (const float*)d_in[3];
    const float* bi     = (const float*)d_in[4];
    const float* Ws     = (const float*)d_in[5];
    const float* bs     = (const float*)d_in[6];
    const float* Wo     = (const float*)d_in[7];
    const float* bo     = (const float*)d_in[8];

    // Workspace layout identical to R3 (verified-running footprint).
    char* w = (char*)d_ws;
    float* P      = (float*)w;              w += (size_t)T * B * SIXH * 4;      // 100.7 MB
    float* Etab   = (float*)w;              w += (size_t)NEMB * SIXH * 4;       //   3.7 MB
    float* ps     = (float*)w;              w += (size_t)B * FIVEH * 4;         //   2.6 MB
    float* h      = (float*)w;              w += (size_t)B * H * 4;
    float* c      = (float*)w;              w += (size_t)B * H * 4;
    _Float16* hhi = (_Float16*)w;           w += (size_t)B * H * 2;
    _Float16* hlo = (_Float16*)w;           w += (size_t)B * H * 2;
    int* eidx     = (int*)w;                w += 512;
    int* bar      = (int*)w;                w += 16384;                          // NWG*16 flags (padded)
    _Float16* Xhi = (_Float16*)w;           w += (size_t)T * B * KTOT * 2;      //  16.8 MB
    _Float16* Xlo = (_Float16*)w;           w += (size_t)T * B * KTOT * 2;
    _Float16* WiThi = (_Float16*)w;         w += (size_t)SIXH * KTOT * 2;       //  25.2 MB
    _Float16* WiTlo = (_Float16*)w;         w += (size_t)SIXH * KTOT * 2;
    _Float16* WsThi = (_Float16*)w;         w += (size_t)FIVEH * H * 2;         //  10.5 MB
    _Float16* WsTlo = (_Float16*)w;         w += (size_t)FIVEH * H * 2;
    // WoT aliases Xhi (Xhi/Xlo dead after big_gemm; cvt_woT runs after big_gemm)
    float* WoT    = (float*)Xhi;

    float* dists = (float*)d_out;
    float* comms = dists + (size_t)T * B * C;

    init_kernel<<<512, 256, 0, stream>>>(h, c, hhi, hlo, eidx, bar);
    cvt_x<<<(T * B * KTOT) / (256 * 4), 256, 0, stream>>>(X, Xhi, Xlo);
    cvt_wT<KTOT, SIXH><<<dim3(SIXH / 32, KTOT / 32), 256, 0, stream>>>(Wi, WiThi, WiTlo);
    cvt_wT<H, FIVEH><<<dim3(FIVEH / 32, H / 32), 256, 0, stream>>>(Ws, WsThi, WsTlo);
    etab_kernel<<<dim3(SIXH / 256, NEMB), 256, 0, stream>>>(embed, Wi, Etab);
    big_gemm_mfma<<<dim3(SIXH / 128, (T * B) / 128), 256, 0, stream>>>(Xhi, Xlo, WiThi, WiTlo, bi, P);
    cvt_woT<<<dim3(H / 256), 256, 0, stream>>>(Wo, WoT);   // after big_gemm: Xhi space reused

    void* args[] = {(void*)&P, (void*)&Etab, (void*)&bs, (void*)&WsThi, (void*)&WsTlo,
                    (void*)&hhi, (void*)&hlo, (void*)&ps, (void*)&WoT, (void*)&bo,
                    (void*)&labels, (void*)&dists, (void*)&comms, (void*)&bar};
    hipError_t err = hipLaunchCooperativeKernel((void*)fused_loop, dim3(NWG), dim3(256),
                                                args, 0, stream);
    if (err != hipSuccess) {
        // fallback: original per-timestep loop
        for (int t = 0; t < T; ++t) {
            ps_mfma<<<dim3(FIVEH / 64, B / 64), 256, 0, stream>>>(hhi, hlo, WsThi, WsTlo, ps);
            gate_kernel<<<dim3(H / 256, B), 256, 0, stream>>>(P, Etab, ps, bs, eidx, h, c, hhi, hlo, t);
            pred_kernel<<<B, 256, 0, stream>>>(h, Wo, bo, labels, dists, comms, eidx, t);
        }
    }
}

// Round 10
// 2390.687 us; speedup vs baseline: 2.5740x; 1.0218x over previous
//
#include <hip/hip_runtime.h>
#include <math.h>

#define H    1024
#define C    151
#define E    200
#define DIN  2048
#define T    32
#define B    128
#define SIXH  (6*H)   // 6144
#define FIVEH (5*H)   // 5120
#define KTOT  DIN     // 2048
#define NEMB  (C+1)   // 152
#define NWG   160     // persistent blocks; 160*32 = 5120 cols
#define COLS  32      // ps columns per WG
#define GUARD (1 << 20)   // spin bailout: bounded wrong-answer beats container-killing hang

typedef _Float16 f16x8 __attribute__((ext_vector_type(8)));
typedef _Float16 f16x4 __attribute__((ext_vector_type(4)));
typedef float    f32x4 __attribute__((ext_vector_type(4)));

#define GLOAD_LDS16(g, l) __builtin_amdgcn_global_load_lds( \
    (const __attribute__((address_space(1))) unsigned int*)(g), \
    (__attribute__((address_space(3))) unsigned int*)(l), 16, 0, 0)

// ---- flag-array grid barrier (R3/R9 verified), split into arrive/wait ----
// arrive + wait back-to-back == R9's verified gbar, instruction for instruction.
// The split lets a WG do LOCAL work (pred/argmax) between releasing its flag
// and waiting for the others — absorbing that work into its own wait-slack.
__device__ __forceinline__ void gbar_arrive(int* slots, int tid) {
    __syncthreads();   // drains this WG's stores (vmcnt 0 at s_barrier) before release RMW
    if (tid == 0)
        __hip_atomic_fetch_add(&slots[blockIdx.x * 16], 1,
                               __ATOMIC_ACQ_REL, __HIP_MEMORY_SCOPE_AGENT);
}
__device__ __forceinline__ void gbar_wait(int* slots, int tid, int val) {
    int ok, guard = 0;
    do {
        int v = val;
        if (tid < NWG)
            v = __hip_atomic_load(&slots[tid * 16],
                                  __ATOMIC_RELAXED, __HIP_MEMORY_SCOPE_AGENT);
        ok = __syncthreads_and(v >= val);
        if (!ok) __builtin_amdgcn_s_sleep(1);
    } while (!ok && ++guard < GUARD);
    __builtin_amdgcn_fence(__ATOMIC_ACQUIRE, "agent");
}

// ---------------- init: zero h, c, hhi, hlo, eidx, barrier slots ----------------
__global__ void init_kernel(float* h, float* c, _Float16* hhi, _Float16* hlo,
                            int* eidx, int* bar) {
    int i = blockIdx.x * blockDim.x + threadIdx.x;
    if (i < B * H) {
        h[i] = 0.f; c[i] = 0.f;
        hhi[i] = (_Float16)0.f; hlo[i] = (_Float16)0.f;
    }
    if (i < B) eidx[i] = 0;
    if (i < NWG * 16) bar[i] = 0;
}

// ---------------- X [4096][2048] fp32 -> hi/lo fp16 (same layout) ----------------
__global__ void cvt_x(const float* __restrict__ X, _Float16* __restrict__ hi,
                      _Float16* __restrict__ lo) {
    size_t i = ((size_t)blockIdx.x * 256 + threadIdx.x) * 4;
    float4 v = *(const float4*)(X + i);
    f16x4 h, l;
    h.x = (_Float16)v.x; l.x = (_Float16)(v.x - (float)h.x);
    h.y = (_Float16)v.y; l.y = (_Float16)(v.y - (float)h.y);
    h.z = (_Float16)v.z; l.z = (_Float16)(v.z - (float)h.z);
    h.w = (_Float16)v.w; l.w = (_Float16)(v.w - (float)h.w);
    *(f16x4*)(hi + i) = h;
    *(f16x4*)(lo + i) = l;
}

// ---------------- W [KR][NC] fp32 -> out [NC][KR] hi/lo fp16 (transposed) ----------------
template<int KR, int NC>
__global__ void cvt_wT(const float* __restrict__ W, _Float16* __restrict__ hi,
                       _Float16* __restrict__ lo) {
    __shared__ float tile[32][33];
    int n0 = blockIdx.x * 32, k0 = blockIdx.y * 32;
    int tx = threadIdx.x & 31, ty = threadIdx.x >> 5;   // ty 0..7
    #pragma unroll
    for (int i = 0; i < 4; ++i) {
        int k = ty + i * 8;
        tile[k][tx] = W[(size_t)(k0 + k) * NC + n0 + tx];
    }
    __syncthreads();
    #pragma unroll
    for (int i = 0; i < 4; ++i) {
        int n = ty + i * 8;
        float v = tile[tx][n];              // = W[k0+tx][n0+n]
        _Float16 h = (_Float16)v;
        size_t o = (size_t)(n0 + n) * KR + k0 + tx;
        hi[o] = h;
        lo[o] = (_Float16)(v - (float)h);
    }
}

// ---------------- Wo [H][C] fp32 -> WoT [C][H] ----------------
__global__ void cvt_woT(const float* __restrict__ Wo, float* __restrict__ WoT) {
    int k = blockIdx.x * 256 + threadIdx.x;  // 0..H-1
    for (int c = 0; c < C; ++c)
        WoT[(size_t)c * H + k] = Wo[(size_t)k * C + c];
}

// ---------------- Etab[k][n] = sum_e embed[k][e] * Wi[DIN+e][n]  (fp32) ----------------
__global__ void etab_kernel(const float* __restrict__ embed,
                            const float* __restrict__ Wi,
                            float* __restrict__ Etab) {
    int n = blockIdx.x * 256 + threadIdx.x;
    int k = blockIdx.y;
    const float* wp = Wi + (size_t)DIN * SIXH + n;
    const float* ep = embed + k * E;
    float acc = 0.f;
    #pragma unroll 8
    for (int e = 0; e < E; ++e)
        acc = fmaf(ep[e], wp[(size_t)e * SIXH], acc);
    Etab[(size_t)k * SIXH + n] = acc;
}

// ---------------- P = X @ Wi_x + bi, fp16x3 MFMA. tile 128x128, 4 waves x 64x64 ----------
__global__ __launch_bounds__(256) void big_gemm_mfma(
    const _Float16* __restrict__ Ahi, const _Float16* __restrict__ Alo,
    const _Float16* __restrict__ Bhi, const _Float16* __restrict__ Blo,
    const float* __restrict__ bi, float* __restrict__ P)
{
    __shared__ __align__(16) _Float16 sAh[128 * 32];
    __shared__ __align__(16) _Float16 sAl[128 * 32];
    __shared__ __align__(16) _Float16 sBh[128 * 32];
    __shared__ __align__(16) _Float16 sBl[128 * 32];
    const int tid = threadIdx.x;
    const int n0 = blockIdx.x * 128;
    const int m0 = blockIdx.y * 128;
    const int lane = tid & 63, w = tid >> 6;
    const int wm = (w >> 1) * 64, wn = (w & 1) * 64;
    const int lr = lane & 15, lq = lane >> 4;

    f32x4 acc[4][4];
    #pragma unroll
    for (int i = 0; i < 4; ++i)
        #pragma unroll
        for (int j = 0; j < 4; ++j)
            acc[i][j] = (f32x4){0.f, 0.f, 0.f, 0.f};

    const int row0 = tid >> 2;        // 0..63
    const int kc = tid & 3;
    const int kcs = kc ^ ((row0 >> 1) & 3);   // swizzled source chunk
    const int sw = (lq ^ ((lr >> 1) & 3)) * 8; // swizzled read slot (halves)

    for (int k0 = 0; k0 < KTOT; k0 += 32) {
        #pragma unroll
        for (int i = 0; i < 2; ++i) {
            int row = row0 + i * 64;
            size_t ga = (size_t)(m0 + row) * KTOT + k0 + kcs * 8;
            size_t gb = (size_t)(n0 + row) * KTOT + k0 + kcs * 8;
            int loff = (i * 256 + tid) * 8;        // halves (linear dest)
            GLOAD_LDS16(Ahi + ga, sAh + loff);
            GLOAD_LDS16(Alo + ga, sAl + loff);
            GLOAD_LDS16(Bhi + gb, sBh + loff);
            GLOAD_LDS16(Blo + gb, sBl + loff);
        }
        __syncthreads();
        f16x8 ah[4], al[4], bh[4], bl[4];
        #pragma unroll
        for (int i = 0; i < 4; ++i) {
            ah[i] = *(const f16x8*)&sAh[(wm + i * 16 + lr) * 32 + sw];
            al[i] = *(const f16x8*)&sAl[(wm + i * 16 + lr) * 32 + sw];
            bh[i] = *(const f16x8*)&sBh[(wn + i * 16 + lr) * 32 + sw];
            bl[i] = *(const f16x8*)&sBl[(wn + i * 16 + lr) * 32 + sw];
        }
        #pragma unroll
        for (int i = 0; i < 4; ++i)
            #pragma unroll
            for (int j = 0; j < 4; ++j) {
                acc[i][j] = __builtin_amdgcn_mfma_f32_16x16x32_f16(ah[i], bh[j], acc[i][j], 0, 0, 0);
                acc[i][j] = __builtin_amdgcn_mfma_f32_16x16x32_f16(ah[i], bl[j], acc[i][j], 0, 0, 0);
                acc[i][j] = __builtin_amdgcn_mfma_f32_16x16x32_f16(al[i], bh[j], acc[i][j], 0, 0, 0);
            }
        __syncthreads();
    }
    #pragma unroll
    for (int i = 0; i < 4; ++i)
        #pragma unroll
        for (int j = 0; j < 4; ++j) {
            int gcol = n0 + wn + j * 16 + lr;
            float bv = bi[gcol];
            #pragma unroll
            for (int r = 0; r < 4; ++r) {
                int grow = m0 + wm + i * 16 + lq * 4 + r;
                P[(size_t)grow * SIXH + gcol] = acc[i][j][r] + bv;
            }
        }
}

// phase-1 h-load/compute macros: even/odd double buffer, 4 k0-groups per block,
// fully static indexing (no runtime-indexed reg arrays -> no scratch).
// Accumulation order is k-ascending, identical to R9 (bit-identical numerics).
#define H_LOAD(Wa, Wl, kbase)                                                  \
    _Pragma("unroll") for (int p = 0; p < 4; ++p)                              \
    _Pragma("unroll") for (int i = 0; i < 2; ++i) {                            \
        size_t ho = (size_t)(mrow0 + i * 16 + lr) * H + (kbase) + p * 32 + lq * 8; \
        Wa[p][i] = *(const f16x8*)&hhi[ho];                                    \
        Wl[p][i] = *(const f16x8*)&hlo[ho];                                    \
    }

#define H_COMP(Wa, Wl, kbase)                                                  \
    _Pragma("unroll") for (int p = 0; p < 4; ++p) {                            \
        const int k0 = (kbase) + p * 32;                                       \
        f16x8 bh[2], bl[2];                                                    \
        _Pragma("unroll") for (int j = 0; j < 2; ++j) {                        \
            int col = j * 16 + lr;                                             \
            int off = (col * (H * 2) + (k0 + lq * 8) * 2) ^ ((col & 7) << 4);  \
            bh[j] = *(const f16x8*)((const char*)sBh + off);                   \
            bl[j] = *(const f16x8*)((const char*)sBl + off);                   \
        }                                                                      \
        _Pragma("unroll") for (int i = 0; i < 2; ++i)                          \
        _Pragma("unroll") for (int j = 0; j < 2; ++j) {                        \
            acc[i][j] = __builtin_amdgcn_mfma_f32_16x16x32_f16(Wa[p][i], bh[j], acc[i][j], 0, 0, 0); \
            acc[i][j] = __builtin_amdgcn_mfma_f32_16x16x32_f16(Wa[p][i], bl[j], acc[i][j], 0, 0, 0); \
            acc[i][j] = __builtin_amdgcn_mfma_f32_16x16x32_f16(Wl[p][i], bh[j], acc[i][j], 0, 0, 0); \
        }                                                                      \
    }

// ================= persistent fused timestep loop (cooperative launch) =================
// R9-verified structure + (1) pred/argmax moved between barrier-B arrive and wait
// (runs in this WG's own wait-slack; uses only WG-local data), (2) phase-1 h loads
// software-pipelined 1 block (8 loads) ahead to cover post-fence L3 latency at
// 1 wave/SIMD occupancy.
__global__ __launch_bounds__(256, 1) void fused_loop(
    const float* __restrict__ P,
    const float* __restrict__ Etab,
    const float* __restrict__ bs,
    const _Float16* __restrict__ WsThi,
    const _Float16* __restrict__ WsTlo,
    _Float16* __restrict__ hhi,
    _Float16* __restrict__ hlo,
    float* __restrict__ ps,
    const float* __restrict__ WoT,
    const float* __restrict__ bo,
    const int* __restrict__ labels,
    float* __restrict__ dists,
    float* __restrict__ comms,
    int* bar)
{
    __shared__ __align__(16) _Float16 sBh[COLS * H];   // 64 KB, XOR-swizzled
    __shared__ __align__(16) _Float16 sBl[COLS * H];   // 64 KB
    __shared__ __align__(16) float hs[H];              // 4 KB (h_new row for pred)
    __shared__ float vals[256];
    __shared__ int   idxs[256];
    __shared__ int   s_eidx;

    const int wg  = blockIdx.x;
    const int tid = threadIdx.x;
    const int n0  = wg * COLS;
    const int lane = tid & 63, w = tid >> 6;
    const int lr = lane & 15, lq = lane >> 4;

    // ---- stage Ws slice into LDS, swizzled: granule byte ^= (col&7)<<4 ----
    for (int gi = tid; gi < COLS * (H / 8); gi += 256) {
        int col = gi >> 7;          // 128 granules of 16B per col
        int kg  = gi & 127;
        int dst = (col * (H * 2) + kg * 16) ^ ((col & 7) << 4);   // bytes
        *(f16x8*)((char*)sBh + dst) = *(const f16x8*)&WsThi[(size_t)(n0 + col) * H + kg * 8];
        *(f16x8*)((char*)sBl + dst) = *(const f16x8*)&WsTlo[(size_t)(n0 + col) * H + kg * 8];
    }

    float creg[4] = {0.f, 0.f, 0.f, 0.f};   // c-state, j = jj*256 + tid
    float bsr[4][5];
    if (wg < B) {
        #pragma unroll
        for (int jj = 0; jj < 4; ++jj)
            #pragma unroll
            for (int k = 0; k < 5; ++k)
                bsr[jj][k] = bs[k * H + jj * 256 + tid];
    }
    if (tid == 0) s_eidx = 0;
    __syncthreads();     // local staging done; cross-WG inputs are stream-ordered

    const int mrow0 = w * 32;
    int bval = 0;

    for (int t = 0; t < T; ++t) {
        int eidx_cur = s_eidx;     // feedback embedding index for this step

        // ---------- phase 1: ps[:, n0:n0+32] = (h) @ Ws-slice, fp16x3 ----------
        f32x4 acc[2][2];
        #pragma unroll
        for (int i = 0; i < 2; ++i)
            #pragma unroll
            for (int j = 0; j < 2; ++j)
                acc[i][j] = (f32x4){0.f, 0.f, 0.f, 0.f};

        {
            f16x8 Aa[4][2], Al_[4][2], Ba[4][2], Bl_[4][2];
            H_LOAD(Aa, Al_, 0)
            H_LOAD(Ba, Bl_, 128)
            H_COMP(Aa, Al_, 0)
            H_LOAD(Aa, Al_, 256)
            H_COMP(Ba, Bl_, 128)
            H_LOAD(Ba, Bl_, 384)
            H_COMP(Aa, Al_, 256)
            H_LOAD(Aa, Al_, 512)
            H_COMP(Ba, Bl_, 384)
            H_LOAD(Ba, Bl_, 640)
            H_COMP(Aa, Al_, 512)
            H_LOAD(Aa, Al_, 768)
            H_COMP(Ba, Bl_, 640)
            H_LOAD(Ba, Bl_, 896)
            H_COMP(Aa, Al_, 768)
            H_COMP(Ba, Bl_, 896)
        }
        #pragma unroll
        for (int i = 0; i < 2; ++i)
            #pragma unroll
            for (int j = 0; j < 2; ++j)
                #pragma unroll
                for (int r = 0; r < 4; ++r)
                    ps[(size_t)(mrow0 + i * 16 + lq * 4 + r) * FIVEH + n0 + j * 16 + lr] = acc[i][j][r];

        // ---- T14 prefetch: P-row (cold HBM) + Etab-row into regs; latency hides
        // under barrier arrival/poll. Independent of ps/h, so legal pre-barrier. ----
        float pf[4][6], pe[4][6];
        if (wg < B) {
            const float* prow = P + (size_t)(t * B + wg) * SIXH;
            const float* erow = Etab + (size_t)eidx_cur * SIXH;
            #pragma unroll
            for (int jj = 0; jj < 4; ++jj)
                #pragma unroll
                for (int k = 0; k < 6; ++k) {
                    pf[jj][k] = prow[k * H + jj * 256 + tid];
                    pe[jj][k] = erow[k * H + jj * 256 + tid];
                }
        }

        ++bval;
        gbar_arrive(bar, tid);
        gbar_wait(bar, tid, bval);

        // ---------- phase 2: gate for b = wg; then arrive; pred/argmax in wait-slack ----
        if (wg < B) {
            const int b = wg;
            const float* psr = ps + (size_t)b * FIVEH;
            #pragma unroll
            for (int jj = 0; jj < 4; ++jj) {
                int j = jj * 256 + tid;
                float gv[5];
                #pragma unroll
                for (int k = 0; k < 5; ++k)
                    gv[k] = pf[jj][k] + pe[jj][k] + psr[k * H + j] + bsr[jj][k];
                float pi5 = pf[jj][5] + pe[jj][5];
                float ig = 1.f / (1.f + expf(-gv[0]));
                float fg = 1.f / (1.f + expf(-gv[1]));
                float mi = tanhf(gv[2]);
                float og = 1.f / (1.f + expf(-gv[3]));
                float hw = 1.f / (1.f + expf(-gv[4]));
                float cn = ig * mi + fg * creg[jj];
                float out = og * tanhf(cn);
                float hn = hw * out + (1.f - hw) * pi5;
                creg[jj] = cn;
                hs[j] = hn;
                _Float16 hh = (_Float16)hn;
                hhi[(size_t)b * H + j] = hh;
                hlo[(size_t)b * H + j] = (_Float16)(hn - (float)hh);
            }
        }
        // arrive releases h(t) for other WGs; the __syncthreads inside arrive also
        // makes hs[] visible WG-locally for the pred below.
        ++bval;
        gbar_arrive(bar, tid);

        if (wg < B) {
            // ---- pred + argmax: purely WG-local (hs LDS, immutable WoT/bo/labels,
            // dists/comms have no cross-WG reader, s_eidx is LDS). Runs during this
            // WG's own barrier wait-slack instead of on the serial chain. ----
            const int b = wg;
            float predv = 0.f;
            if (tid < C) {
                const float* wp = WoT + (size_t)tid * H;
                float a0 = bo[tid], a1 = 0.f, a2 = 0.f, a3 = 0.f;
                #pragma unroll 4
                for (int k = 0; k < H; k += 4) {
                    float4 w4 = *(const float4*)&wp[k];
                    float4 h4 = *(const float4*)&hs[k];
                    a0 = fmaf(h4.x, w4.x, a0);
                    a1 = fmaf(h4.y, w4.y, a1);
                    a2 = fmaf(h4.z, w4.z, a2);
                    a3 = fmaf(h4.w, w4.w, a3);
                }
                predv = (a0 + a1) + (a2 + a3);
                dists[(size_t)(t * B + b) * C + tid] = predv;
            }
            vals[tid] = (tid >= 1 && tid < C) ? predv : -1e30f;
            idxs[tid] = tid;
            __syncthreads();
            for (int s = 128; s > 0; s >>= 1) {
                if (tid < s) {
                    float v2 = vals[tid + s];
                    int   i2 = idxs[tid + s];
                    if (v2 > vals[tid] || (v2 == vals[tid] && i2 < idxs[tid])) {
                        vals[tid] = v2;
                        idxs[tid] = i2;
                    }
                }
                __syncthreads();
            }
            if (tid == 0) {
                int nzp = idxs[0];
                int lt = labels[t * B + b];
                int comm = (lt == 0) ? nzp : lt;
                comms[t * B + b] = (float)comm;
                s_eidx = comm + 1;   // read next step after gbar_wait's syncthreads
            }
        }
        gbar_wait(bar, tid, bval);
    }
}

// ================= fallback per-timestep kernels (used only if coop launch fails) =====
__global__ __launch_bounds__(256) void ps_mfma(
    const _Float16* __restrict__ Ahi, const _Float16* __restrict__ Alo,
    const _Float16* __restrict__ Bhi, const _Float16* __restrict__ Blo,
    float* __restrict__ ps)
{
    __shared__ __align__(16) _Float16 sAh[64 * 32];
    __shared__ __align__(16) _Float16 sAl[64 * 32];
    __shared__ __align__(16) _Float16 sBh[64 * 32];
    __shared__ __align__(16) _Float16 sBl[64 * 32];
    const int tid = threadIdx.x;
    const int n0 = blockIdx.x * 64;
    const int m0 = blockIdx.y * 64;
    const int lane = tid & 63, w = tid >> 6;
    const int wm = (w >> 1) * 32, wn = (w & 1) * 32;
    const int lr = lane & 15, lq = lane >> 4;

    f32x4 acc[2][2];
    #pragma unroll
    for (int i = 0; i < 2; ++i)
        #pragma unroll
        for (int j = 0; j < 2; ++j)
            acc[i][j] = (f32x4){0.f, 0.f, 0.f, 0.f};

    const int row = tid >> 2;
    const int kc = tid & 3;

    for (int k0 = 0; k0 < H; k0 += 32) {
        size_t ga = (size_t)(m0 + row) * H + k0 + kc * 8;
        size_t gb = (size_t)(n0 + row) * H + k0 + kc * 8;
        int loff = tid * 8;
        GLOAD_LDS16(Ahi + ga, sAh + loff);
        GLOAD_LDS16(Alo + ga, sAl + loff);
        GLOAD_LDS16(Bhi + gb, sBh + loff);
        GLOAD_LDS16(Blo + gb, sBl + loff);
        __syncthreads();
        f16x8 ah[2], al[2], bh[2], bl[2];
        #pragma unroll
        for (int i = 0; i < 2; ++i) {
            ah[i] = *(const f16x8*)&sAh[(wm + i * 16 + lr) * 32 + lq * 8];
            al[i] = *(const f16x8*)&sAl[(wm + i * 16 + lr) * 32 + lq * 8];
            bh[i] = *(const f16x8*)&sBh[(wn + i * 16 + lr) * 32 + lq * 8];
            bl[i] = *(const f16x8*)&sBl[(wn + i * 16 + lr) * 32 + lq * 8];
        }
        #pragma unroll
        for (int i = 0; i < 2; ++i)
            #pragma unroll
            for (int j = 0; j < 2; ++j) {
                acc[i][j] = __builtin_amdgcn_mfma_f32_16x16x32_f16(ah[i], bh[j], acc[i][j], 0, 0, 0);
                acc[i][j] = __builtin_amdgcn_mfma_f32_16x16x32_f16(ah[i], bl[j], acc[i][j], 0, 0, 0);
                acc[i][j] = __builtin_amdgcn_mfma_f32_16x16x32_f16(al[i], bh[j], acc[i][j], 0, 0, 0);
            }
        __syncthreads();
    }
    #pragma unroll
    for (int i = 0; i < 2; ++i)
        #pragma unroll
        for (int j = 0; j < 2; ++j) {
            int gcol = n0 + wn + j * 16 + lr;
            #pragma unroll
            for (int r = 0; r < 4; ++r) {
                int grow = m0 + wm + i * 16 + lq * 4 + r;
                ps[(size_t)grow * FIVEH + gcol] = acc[i][j][r];
            }
        }
}

__global__ void gate_kernel(const float* __restrict__ P,
                            const float* __restrict__ Etab,
                            const float* __restrict__ ps,
                            const float* __restrict__ bs,
                            const int* __restrict__ eidx,
                            float* __restrict__ h,
                            float* __restrict__ c,
                            _Float16* __restrict__ hhi,
                            _Float16* __restrict__ hlo,
                            int t) {
    int j = blockIdx.x * 256 + threadIdx.x;
    int b = blockIdx.y;
    const float* prow = P + (size_t)(t * B + b) * SIXH;
    const float* erow = Etab + (size_t)eidx[b] * SIXH;
    const float* psr  = ps + (size_t)b * FIVEH;
    float g[5];
    #pragma unroll
    for (int k = 0; k < 5; ++k) {
        int col = k * H + j;
        g[k] = prow[col] + erow[col] + psr[col] + bs[col];
    }
    float pi5 = prow[5 * H + j] + erow[5 * H + j];
    float ig = 1.f / (1.f + expf(-g[0]));
    float fg = 1.f / (1.f + expf(-g[1]));
    float mi = tanhf(g[2]);
    float og = 1.f / (1.f + expf(-g[3]));
    float hw = 1.f / (1.f + expf(-g[4]));
    float cv = c[b * H + j];
    float cn = ig * mi + fg * cv;
    float out = og * tanhf(cn);
    float hn = hw * out + (1.f - hw) * pi5;
    c[b * H + j] = cn;
    h[b * H + j] = hn;
    _Float16 hh = (_Float16)hn;
    hhi[b * H + j] = hh;
    hlo[b * H + j] = (_Float16)(hn - (float)hh);
}

__global__ void pred_kernel(const float* __restrict__ h,
                            const float* __restrict__ Wo,
                            const float* __restrict__ bo,
                            const int* __restrict__ labels,
                            float* __restrict__ dists,
                            float* __restrict__ comms,
                            int* __restrict__ eidx,
                            int t) {
    __shared__ float hsb[H];
    __shared__ float vals[256];
    __shared__ int   idxs[256];
    int tid = threadIdx.x;
    int b = blockIdx.x;
    for (int i = tid; i < H / 4; i += 256)
        *(float4*)&hsb[i * 4] = *(const float4*)&h[b * H + i * 4];
    __syncthreads();
    float pred = 0.f;
    if (tid < C) {
        pred = bo[tid];
        #pragma unroll 8
        for (int k = 0; k < H; ++k)
            pred = fmaf(hsb[k], Wo[k * C + tid], pred);
        dists[(size_t)(t * B + b) * C + tid] = pred;
    }
    vals[tid] = (tid >= 1 && tid < C) ? pred : -1e30f;
    idxs[tid] = tid;
    __syncthreads();
    for (int s = 128; s > 0; s >>= 1) {
        if (tid < s) {
            float v2 = vals[tid + s];
            int   i2 = idxs[tid + s];
            if (v2 > vals[tid] || (v2 == vals[tid] && i2 < idxs[tid])) {
                vals[tid] = v2;
                idxs[tid] = i2;
            }
        }
        __syncthreads();
    }
    if (tid == 0) {
        int nzp = idxs[0];
        int lt = labels[t * B + b];
        int comm = (lt == 0) ? nzp : lt;
        comms[t * B + b] = (float)comm;
        eidx[b] = comm + 1;
    }
}

extern "C" void kernel_launch(void* const* d_in, const int* in_sizes, int n_in,
                              void* d_out, int out_size, void* d_ws, size_t ws_size,
                              hipStream_t stream) {
    const float* X      = (const float*)d_in[0];
    const int*   labels = (const int*)  d_in[1];
    const float* embed  = (const float*)d_in[2];
    const float* Wi     = (const float*)d_in[3];
    const float* bi     = (const float*)d_in[4];
    const float* Ws     = (const float*)d_in[5];
    const float* bs     = (const float*)d_in[6];
    const float* Wo     = (const float*)d_in[7];
    const float* bo     = (const float*)d_in[8];

    // Workspace layout identical to R3/R9 (verified-running footprint).
    char* w = (char*)d_ws;
    float* P      = (float*)w;              w += (size_t)T * B * SIXH * 4;      // 100.7 MB
    float* Etab   = (float*)w;              w += (size_t)NEMB * SIXH * 4;       //   3.7 MB
    float* ps     = (float*)w;              w += (size_t)B * FIVEH * 4;         //   2.6 MB
    float* h      = (float*)w;              w += (size_t)B * H * 4;
    float* c      = (float*)w;              w += (size_t)B * H * 4;
    _Float16* hhi = (_Float16*)w;           w += (size_t)B * H * 2;
    _Float16* hlo = (_Float16*)w;           w += (size_t)B * H * 2;
    int* eidx     = (int*)w;                w += 512;
    int* bar      = (int*)w;                w += 16384;                          // NWG*16 flags (padded)
    _Float16* Xhi = (_Float16*)w;           w += (size_t)T * B * KTOT * 2;      //  16.8 MB
    _Float16* Xlo = (_Float16*)w;           w += (size_t)T * B * KTOT * 2;
    _Float16* WiThi = (_Float16*)w;         w += (size_t)SIXH * KTOT * 2;       //  25.2 MB
    _Float16* WiTlo = (_Float16*)w;         w += (size_t)SIXH * KTOT * 2;
    _Float16* WsThi = (_Float16*)w;         w += (size_t)FIVEH * H * 2;         //  10.5 MB
    _Float16* WsTlo = (_Float16*)w;         w += (size_t)FIVEH * H * 2;
    // WoT aliases Xhi (Xhi/Xlo dead after big_gemm; cvt_woT runs after big_gemm)
    float* WoT    = (float*)Xhi;

    float* dists = (float*)d_out;
    float* comms = dists + (size_t)T * B * C;

    init_kernel<<<512, 256, 0, stream>>>(h, c, hhi, hlo, eidx, bar);
    cvt_x<<<(T * B * KTOT) / (256 * 4), 256, 0, stream>>>(X, Xhi, Xlo);
    cvt_wT<KTOT, SIXH><<<dim3(SIXH / 32, KTOT / 32), 256, 0, stream>>>(Wi, WiThi, WiTlo);
    cvt_wT<H, FIVEH><<<dim3(FIVEH / 32, H / 32), 256, 0, stream>>>(Ws, WsThi, WsTlo);
    etab_kernel<<<dim3(SIXH / 256, NEMB), 256, 0, stream>>>(embed, Wi, Etab);
    big_gemm_mfma<<<dim3(SIXH / 128, (T * B) / 128), 256, 0, stream>>>(Xhi, Xlo, WiThi, WiTlo, bi, P);
    cvt_woT<<<dim3(H / 256), 256, 0, stream>>>(Wo, WoT);   // after big_gemm: Xhi space reused

    void* args[] = {(void*)&P, (void*)&Etab, (void*)&bs, (void*)&WsThi, (void*)&WsTlo,
                    (void*)&hhi, (void*)&hlo, (void*)&ps, (void*)&WoT, (void*)&bo,
                    (void*)&labels, (void*)&dists, (void*)&comms, (void*)&bar};
    hipError_t err = hipLaunchCooperativeKernel((void*)fused_loop, dim3(NWG), dim3(256),
                                                args, 0, stream);
    if (err != hipSuccess) {
        // fallback: original per-timestep loop
        for (int t = 0; t < T; ++t) {
            ps_mfma<<<dim3(FIVEH / 64, B / 64), 256, 0, stream>>>(hhi, hlo, WsThi, WsTlo, ps);
            gate_kernel<<<dim3(H / 256, B), 256, 0, stream>>>(P, Etab, ps, bs, eidx, h, c, hhi, hlo, t);
            pred_kernel<<<B, 256, 0, stream>>>(h, Wo, bo, labels, dists, comms, eidx, t);
        }
    }
}